// Round 1
// baseline (1046.164 us; speedup 1.0000x reference)
//
#include <hip/hip_runtime.h>
#include <math.h>

#define H_ 768
#define W_ 768
#define TILE 32
#define EXT 36     // TILE + 4  (halo 2 for J/cdv taps)
#define BHALO 40   // TILE + 8  (halo 4 for bayer)
#define EPS_ 1e-6f

// 10 unique 5x5 kernels: 0 cb, 1 sh, 2 sv, 3 sx, 4 sy, 5 px, 6 py, 7 g45, 8 g135, 9 dct
__device__ float g_k5bank[250];

__global__ void init_k5_kernel() {
    int k = threadIdx.x;
    if (k >= 10) return;
    double raw[25];
    const double PI = 3.14159265358979323846;
    for (int i = 0; i < 5; ++i) {
        for (int j = 0; j < 5; ++j) {
            double v = 0.0;
            switch (k) {
                case 0: v = ((i + j) & 1) ? -1.0 : 1.0; break;           // checkerboard
                case 1: v = (j & 1) ? -1.0 : 1.0; break;                 // (-1)^col
                case 2: v = (i & 1) ? -1.0 : 1.0; break;                 // (-1)^row
                case 3: v = sin(2.0 * PI * j / 5.0); break;              // sx
                case 4: v = sin(2.0 * PI * i / 5.0); break;              // sy
                case 5: v = cos(2.0 * PI * j / 5.0); break;              // px
                case 6: v = cos(2.0 * PI * i / 5.0); break;              // py
                case 7:
                case 8: {
                    double theta = (k == 7) ? PI / 4.0 : 3.0 * PI / 4.0;
                    double y = (double)(i - 2), x = (double)(j - 2);
                    double ct = cos(theta), st = sin(theta);
                    double xt = x * ct + y * st;
                    double yt = -x * st + y * ct;
                    double env = exp(-(xt * xt + 0.4225 * yt * yt) / (2.0 * 1.1 * 1.1));
                    v = env * cos(2.0 * PI * xt / 3.0);
                } break;
                case 9: v = cos(PI * (i + 0.5) * 2.0 / 5.0) * cos(PI * (j + 0.5) * 2.0 / 5.0); break;
            }
            raw[i * 5 + j] = v;
        }
    }
    double mean = 0.0;
    for (int i = 0; i < 25; ++i) mean += raw[i];
    mean /= 25.0;
    double s = 0.0;
    for (int i = 0; i < 25; ++i) { raw[i] -= mean; s += fabs(raw[i]); }
    if (s < 1e-6) s = 1e-6;
    for (int i = 0; i < 25; ++i) g_k5bank[k * 25 + i] = (float)(raw[i] / s);
}

__device__ __forceinline__ int refl(int i, int n) {
    i = (i < 0) ? -i : i;
    return (i >= n) ? (2 * n - 2 - i) : i;
}

__global__ __launch_bounds__(256, 2)
void bayer_feat_kernel(const float* __restrict__ in, float* __restrict__ out) {
    __shared__ float sB[BHALO][BHALO + 2];
    __shared__ float sGx[EXT][EXT + 2];
    __shared__ float sGy[EXT][EXT + 2];
    __shared__ float sRG[EXT][EXT + 2];
    __shared__ float sBGc[EXT][EXT + 2];
    __shared__ float sGPD[EXT][EXT + 2];
    __shared__ float sK5[250];

    const int tid = threadIdx.x;
    const int x0 = blockIdx.x * TILE;
    const int y0 = blockIdx.y * TILE;
    const int bz = blockIdx.z;
    const float* __restrict__ inb = in + (size_t)bz * H_ * W_;

    for (int i = tid; i < 250; i += 256) sK5[i] = g_k5bank[i];

    // stage bayer tile + halo 4 (reflect)
    for (int i = tid; i < BHALO * BHALO; i += 256) {
        int iy = i / BHALO, ix = i - iy * BHALO;
        int gy = refl(y0 - 4 + iy, H_);
        int gx = refl(x0 - 4 + ix, W_);
        sB[iy][ix] = inb[gy * W_ + gx];
    }
    __syncthreads();

    const float w5[5] = {1.f, 2.f, 3.f, 2.f, 1.f};

    // extended 36x36 region: gx, gy, rg, bg, gpd
    for (int i = tid; i < EXT * EXT; i += 256) {
        int ey = i / EXT, ex = i - ey * EXT;
        int cy = ey + 2, cx = ex + 2;  // sB coords

        float bmm = sB[cy-1][cx-1], bm0 = sB[cy-1][cx], bmp = sB[cy-1][cx+1];
        float b0m = sB[cy  ][cx-1],                      b0p = sB[cy  ][cx+1];
        float bpm = sB[cy+1][cx-1], bp0 = sB[cy+1][cx], bpp = sB[cy+1][cx+1];
        sGx[ey][ex] = ((bmp - bmm) + 2.f*(b0p - b0m) + (bpp - bpm)) * 0.125f;
        sGy[ey][ex] = ((bpm - bmm) + 2.f*(bp0 - bm0) + (bpp - bmp)) * 0.125f;

        int gyp = y0 - 2 + ey;           // may be virtual (<0 or >=H): only parity used
        int gxp = x0 - 2 + ex;
        int p_r = (int)((unsigned)(gyp + 16) & 1u);
        int p_c = (int)((unsigned)(gxp + 16) & 1u);

        // masked smooth5 sums grouped by tap parity class
        float A0 = 0.f, A1 = 0.f, B0 = 0.f, B1 = 0.f;
        #pragma unroll
        for (int dy = 0; dy < 5; ++dy) {
            const float* row = &sB[cy + dy - 2][0];
            float cs = row[cx-2] + 3.f*row[cx] + row[cx+2];   // dx even -> col parity == p_c
            float cd = 2.f*(row[cx-1] + row[cx+1]);           // dx odd  -> col parity != p_c
            float wy = w5[dy];
            if (dy & 1) { B0 += wy * cs; B1 += wy * cd; }     // row parity != p_r
            else        { A0 += wy * cs; A1 += wy * cd; }     // row parity == p_r
        }
        // reparameterize to absolute parity classes
        float rA0 = p_r ? B0 : A0;   // row-par 0, col-par == p_c
        float rA1 = p_r ? B1 : A1;   // row-par 0, col-par != p_c
        float rB0 = p_r ? A0 : B0;   // row-par 1, col-par == p_c
        float rB1 = p_r ? A1 : B1;   // row-par 1, col-par != p_c
        float n_gb = p_c ? rA1 : rA0;   // (row even, col even)
        float n_b  = p_c ? rA0 : rA1;   // (row even, col odd)
        float n_r  = p_c ? rB1 : rB0;   // (row odd,  col even)
        float n_gr = p_c ? rB0 : rB1;   // (row odd,  col odd)

        // analytic reciprocals of 81*den per class
        float inv_r  = p_r ? (p_c ? 0.05f   : 0.04f) : (p_c ? 0.0625f : 0.05f);
        float inv_b  = p_r ? (p_c ? 0.05f   : 0.0625f) : (p_c ? 0.04f : 0.05f);
        float inv_gr = p_r ? (p_c ? 0.04f   : 0.05f) : (p_c ? 0.05f   : 0.0625f);
        float inv_gb = p_r ? (p_c ? 0.0625f : 0.05f) : (p_c ? 0.05f   : 0.04f);
        float inv_g  = (p_r == p_c) ? 0.024390243902439025f : 0.025f;

        float fr  = n_r  * inv_r;
        float fb  = n_b  * inv_b;
        float fgr = n_gr * inv_gr;
        float fgb = n_gb * inv_gb;
        float fg  = (n_gr + n_gb) * inv_g;

        sRG[ey][ex]  = fr - fg;
        sBGc[ey][ex] = fb - fg;
        sGPD[ey][ex] = fgr - fgb;
    }
    __syncthreads();

    const size_t HW = (size_t)H_ * W_;
    float* __restrict__ outb = out + (size_t)bz * 30 * HW;

    #pragma unroll
    for (int kk = 0; kk < 4; ++kk) {
        int lin = kk * 256 + tid;
        int ty = lin >> 5, tx = lin & 31;
        int cy = ty + 4, cx = tx + 4;
        int gy = y0 + ty, gx = x0 + tx;

        float bmm = sB[cy-1][cx-1], bm0 = sB[cy-1][cx], bmp = sB[cy-1][cx+1];
        float b0m = sB[cy  ][cx-1], b00 = sB[cy  ][cx], b0p = sB[cy  ][cx+1];
        float bpm = sB[cy+1][cx-1], bp0 = sB[cy+1][cx], bpp = sB[cy+1][cx+1];

        float gxv = sGx[ty+2][tx+2];
        float gyv = sGy[ty+2][tx+2];
        float gdm = (-2.f*bmm - bm0 - b0m + b0p + bp0 + 2.f*bpp) * 0.125f;
        float gda = (bm0 + 2.f*bmp - b0m + b0p - 2.f*bpm - bp0) * 0.125f;
        float lap = bm0 + b0m - 4.f*b00 + b0p + bp0;
        float hxx = b0m - 2.f*b00 + b0p;
        float hyy = bm0 - 2.f*b00 + bp0;
        float hxy = (bmm - bmp - bpm + bpp) * 0.25f;
        float gcross = 0.25f * (bm0 + b0m + b0p + bp0);
        float hf = ((bmm + bmp + bpm + bpp) - 2.f*(bm0 + b0m + b0p + bp0) + 4.f*b00) * 0.0625f;

        float grad_mag = sqrtf(gxv*gxv + gyv*gyv + EPS_);
        float hm = 0.5f * (hxx + hyy);
        float hsd = 0.5f * (hxx - hyy);
        float hs = sqrtf(hsd*hsd + hxy*hxy + EPS_);
        float lam_max = hm + hs, lam_min = hm - hs;

        float md  = 0.25f * (gxv + gyv + gdm + gda);
        float m2d = 0.25f * (gxv*gxv + gyv*gyv + gdm*gdm + gda*gda);
        float dir_var = m2d - md * md;

        // 10 unique 5x5 convs
        float s5[10];
        #pragma unroll
        for (int q = 0; q < 10; ++q) s5[q] = 0.f;
        #pragma unroll
        for (int dy = 0; dy < 5; ++dy) {
            #pragma unroll
            for (int dx = 0; dx < 5; ++dx) {
                float v = sB[cy + dy - 2][cx + dx - 2];
                int widx = dy * 5 + dx;
                #pragma unroll
                for (int q = 0; q < 10; ++q) s5[q] = fmaf(sK5[q * 25 + widx], v, s5[q]);
            }
        }

        float gh = 0.5f*(b0m + b00 + b0p) - 0.25f*(sB[cy][cx-2] + sB[cy][cx+2]);
        float gv = 0.5f*(bm0 + b00 + bp0) - 0.25f*(sB[cy-2][cx] + sB[cy+2][cx]);
        float dgc = fabsf(gh - gv);

        // J (smooth5 of gx products) + cdv (box5 moments of rg/bg), reflected taps
        float jxx=0.f, jyy=0.f, jxy=0.f, m1r=0.f, m2r=0.f, m1b=0.f, m2b=0.f;
        #pragma unroll
        for (int dy = -2; dy <= 2; ++dy) {
            int ry = refl(gy + dy, H_) - (y0 - 2);
            float wy = w5[dy + 2];
            #pragma unroll
            for (int dx = -2; dx <= 2; ++dx) {
                int rx = refl(gx + dx, W_) - (x0 - 2);
                float w = wy * w5[dx + 2];
                float a = sGx[ry][rx], b = sGy[ry][rx];
                jxx = fmaf(w, a*a, jxx);
                jyy = fmaf(w, b*b, jyy);
                jxy = fmaf(w, a*b, jxy);
                float r_ = sRG[ry][rx], q_ = sBGc[ry][rx];
                m1r += r_; m2r = fmaf(r_, r_, m2r);
                m1b += q_; m2b = fmaf(q_, q_, m2b);
            }
        }
        const float inv81 = 1.f / 81.f;
        jxx *= inv81; jyy *= inv81; jxy *= inv81;
        float jd = 0.5f * (jxx - jyy);
        float aniso = 2.f * sqrtf(jd*jd + jxy*jxy + EPS_) / (jxx + jyy + EPS_);
        const float inv25 = 0.04f;
        m1r *= inv25; m2r *= inv25; m1b *= inv25; m2b *= inv25;
        float var_r = fmaxf(m2r - m1r*m1r, 0.f);
        float var_b = fmaxf(m2b - m1b*m1b, 0.f);
        float cdv = var_r + var_b;

        float rg  = sRG[ty+2][tx+2];
        float bgv = sBGc[ty+2][tx+2];
        float gpd = sGPD[ty+2][tx+2];
        float chroma = sqrtf(rg*rg + bgv*bgv + EPS_);

        int p_r = gy & 1, p_c = gx & 1;
        float r_m = (p_r == 1 && p_c == 0) ? 1.f : 0.f;
        float b_m = (p_r == 0 && p_c == 1) ? 1.f : 0.f;
        float g_m = (p_r == p_c) ? 1.f : 0.f;
        float gir = (p_r == p_c) ? (b00 - gcross) : 0.f;

        float orient_e = sqrtf(s5[7]*s5[7] + s5[8]*s5[8] + EPS_);
        float cb_e     = fabsf(s5[0]);
        float phase_e  = sqrtf(s5[5]*s5[5] + s5[6]*s5[6] + EPS_);
        float highband = sqrtf(s5[9]*s5[9] + hf*hf + EPS_);

        float* p = outb + (size_t)gy * W_ + gx;
        p[ 0*HW] = gxv;      p[ 1*HW] = gyv;      p[ 2*HW] = gdm;      p[ 3*HW] = gda;
        p[ 4*HW] = grad_mag; p[ 5*HW] = lap;      p[ 6*HW] = lam_max;  p[ 7*HW] = lam_min;
        p[ 8*HW] = aniso;    p[ 9*HW] = dir_var;  p[10*HW] = orient_e; p[11*HW] = r_m;
        p[12*HW] = g_m;      p[13*HW] = b_m;      p[14*HW] = gpd;      p[15*HW] = rg;
        p[16*HW] = bgv;      p[17*HW] = gir;      p[18*HW] = dgc;      p[19*HW] = chroma;
        p[20*HW] = cdv;      p[21*HW] = cb_e;     p[22*HW] = s5[1];    p[23*HW] = s5[2];
        p[24*HW] = s5[1];    p[25*HW] = s5[2];    p[26*HW] = phase_e;  p[27*HW] = s5[3];
        p[28*HW] = s5[4];    p[29*HW] = highband;
    }
}

extern "C" void kernel_launch(void* const* d_in, const int* in_sizes, int n_in,
                              void* d_out, int out_size, void* d_ws, size_t ws_size,
                              hipStream_t stream) {
    const float* bayer = (const float*)d_in[0];
    float* out = (float*)d_out;
    (void)in_sizes; (void)n_in; (void)out_size; (void)d_ws; (void)ws_size;

    init_k5_kernel<<<dim3(1), dim3(64), 0, stream>>>();
    dim3 grid(W_ / TILE, H_ / TILE, 4);
    bayer_feat_kernel<<<grid, dim3(256), 0, stream>>>(bayer, out);
}

// Round 2
// 158.753 us; speedup vs baseline: 6.5899x; 6.5899x over previous
//
#include <hip/hip_runtime.h>
#include <math.h>

#define H_ 768
#define W_ 768
#define TILE 32
#define EXT 36     // TILE + 4  (halo 2 for J/cdv taps)
#define BHALO 40   // TILE + 8  (halo 4 for bayer)
#define EPS_ 1e-6f

// 10 unique 5x5 kernels: 0 cb, 1 sh, 2 sv, 3 sx, 4 sy, 5 px, 6 py, 7 g45, 8 g135, 9 dct
__device__ float g_k5bank[250];

__global__ void init_k5_kernel() {
    int k = threadIdx.x;
    if (k >= 10) return;
    double raw[25];
    const double PI = 3.14159265358979323846;
    for (int i = 0; i < 5; ++i) {
        for (int j = 0; j < 5; ++j) {
            double v = 0.0;
            switch (k) {
                case 0: v = ((i + j) & 1) ? -1.0 : 1.0; break;           // checkerboard
                case 1: v = (j & 1) ? -1.0 : 1.0; break;                 // (-1)^col
                case 2: v = (i & 1) ? -1.0 : 1.0; break;                 // (-1)^row
                case 3: v = sin(2.0 * PI * j / 5.0); break;              // sx
                case 4: v = sin(2.0 * PI * i / 5.0); break;              // sy
                case 5: v = cos(2.0 * PI * j / 5.0); break;              // px
                case 6: v = cos(2.0 * PI * i / 5.0); break;              // py
                case 7:
                case 8: {
                    double theta = (k == 7) ? PI / 4.0 : 3.0 * PI / 4.0;
                    double y = (double)(i - 2), x = (double)(j - 2);
                    double ct = cos(theta), st = sin(theta);
                    double xt = x * ct + y * st;
                    double yt = -x * st + y * ct;
                    double env = exp(-(xt * xt + 0.4225 * yt * yt) / (2.0 * 1.1 * 1.1));
                    v = env * cos(2.0 * PI * xt / 3.0);
                } break;
                case 9: v = cos(PI * (i + 0.5) * 2.0 / 5.0) * cos(PI * (j + 0.5) * 2.0 / 5.0); break;
            }
            raw[i * 5 + j] = v;
        }
    }
    double mean = 0.0;
    for (int i = 0; i < 25; ++i) mean += raw[i];
    mean /= 25.0;
    double s = 0.0;
    for (int i = 0; i < 25; ++i) { raw[i] -= mean; s += fabs(raw[i]); }
    if (s < 1e-6) s = 1e-6;
    for (int i = 0; i < 25; ++i) g_k5bank[k * 25 + i] = (float)(raw[i] / s);
}

__device__ __forceinline__ int refl(int i, int n) {
    i = (i < 0) ? -i : i;
    return (i >= n) ? (2 * n - 2 - i) : i;
}

__global__ __launch_bounds__(256)
void bayer_feat_kernel(const float* __restrict__ in, float* __restrict__ out) {
    __shared__ float  sB[BHALO][BHALO];   // 6400 B
    __shared__ float2 sGG[EXT][EXT];      // (gx, gy)  10368 B
    __shared__ float2 sCD[EXT][EXT];      // (rg, bg)  10368 B
    __shared__ float  sGPD[TILE][TILE];   // gpd at centers, 4096 B
    __shared__ float  sK5[250];           // 1000 B

    const int tid = threadIdx.x;
    const int x0 = blockIdx.x * TILE;
    const int y0 = blockIdx.y * TILE;
    const int bz = blockIdx.z;
    const float* __restrict__ inb = in + (size_t)bz * H_ * W_;

    for (int i = tid; i < 250; i += 256) sK5[i] = g_k5bank[i];

    // stage bayer tile + halo 4 (reflect)
    for (int i = tid; i < BHALO * BHALO; i += 256) {
        int iy = i / BHALO, ix = i - iy * BHALO;
        int gy = refl(y0 - 4 + iy, H_);
        int gx = refl(x0 - 4 + ix, W_);
        sB[iy][ix] = inb[gy * W_ + gx];
    }
    __syncthreads();

    const float w5[5] = {1.f, 2.f, 3.f, 2.f, 1.f};

    // extended 36x36 region, REFLECTION APPLIED AT FILL TIME:
    // value stored at ext (ey,ex) = intermediate evaluated at refl(global pos).
    // (reflect-pad of an intermediate map == intermediate at reflected coord;
    //  reflection preserves parity so the mask/fill parity classes are exact)
    for (int i = tid; i < EXT * EXT; i += 256) {
        int ey = i / EXT, ex = i - ey * EXT;
        int gyv = y0 - 2 + ey;            // may be virtual
        int gxv = x0 - 2 + ex;
        int py = refl(gyv, H_), pxc = refl(gxv, W_);   // in-image reflected pos
        int ry = py - (y0 - 4), rx = pxc - (x0 - 4);   // sB coords, in [2,38)

        float bmm = sB[ry-1][rx-1], bm0 = sB[ry-1][rx], bmp = sB[ry-1][rx+1];
        float b0m = sB[ry  ][rx-1],                      b0p = sB[ry  ][rx+1];
        float bpm = sB[ry+1][rx-1], bp0 = sB[ry+1][rx], bpp = sB[ry+1][rx+1];
        float gxval = ((bmp - bmm) + 2.f*(b0p - b0m) + (bpp - bpm)) * 0.125f;
        float gyval = ((bpm - bmm) + 2.f*(bp0 - bm0) + (bpp - bmp)) * 0.125f;
        sGG[ey][ex] = make_float2(gxval, gyval);

        int p_r = py & 1;
        int p_c = pxc & 1;

        // masked smooth5 sums grouped by tap parity class
        float A0 = 0.f, A1 = 0.f, B0 = 0.f, B1 = 0.f;
        #pragma unroll
        for (int dy = 0; dy < 5; ++dy) {
            const float* row = &sB[ry + dy - 2][0];
            float cs = row[rx-2] + 3.f*row[rx] + row[rx+2];   // dx even -> col parity == p_c
            float cd = 2.f*(row[rx-1] + row[rx+1]);           // dx odd  -> col parity != p_c
            float wy = w5[dy];
            if (dy & 1) { B0 += wy * cs; B1 += wy * cd; }     // row parity != p_r
            else        { A0 += wy * cs; A1 += wy * cd; }     // row parity == p_r
        }
        float rA0 = p_r ? B0 : A0;   // row-par 0, col-par == p_c
        float rA1 = p_r ? B1 : A1;
        float rB0 = p_r ? A0 : B0;   // row-par 1
        float rB1 = p_r ? A1 : B1;
        float n_gb = p_c ? rA1 : rA0;   // (row even, col even)
        float n_b  = p_c ? rA0 : rA1;   // (row even, col odd)
        float n_r  = p_c ? rB1 : rB0;   // (row odd,  col even)
        float n_gr = p_c ? rB0 : rB1;   // (row odd,  col odd)

        float inv_r  = p_r ? (p_c ? 0.05f   : 0.04f)   : (p_c ? 0.0625f : 0.05f);
        float inv_b  = p_r ? (p_c ? 0.05f   : 0.0625f) : (p_c ? 0.04f   : 0.05f);
        float inv_gr = p_r ? (p_c ? 0.04f   : 0.05f)   : (p_c ? 0.05f   : 0.0625f);
        float inv_gb = p_r ? (p_c ? 0.0625f : 0.05f)   : (p_c ? 0.05f   : 0.04f);
        float inv_g  = (p_r == p_c) ? 0.024390243902439025f : 0.025f;

        float fr  = n_r  * inv_r;
        float fb  = n_b  * inv_b;
        float fgr = n_gr * inv_gr;
        float fgb = n_gb * inv_gb;
        float fg  = (n_gr + n_gb) * inv_g;

        sCD[ey][ex] = make_float2(fr - fg, fb - fg);
        if (ey >= 2 && ey < 34 && ex >= 2 && ex < 34)
            sGPD[ey - 2][ex - 2] = fgr - fgb;
    }
    __syncthreads();

    const size_t HW = (size_t)H_ * W_;
    float* __restrict__ outb = out + (size_t)bz * 30 * HW;

    #pragma unroll 1
    for (int kk = 0; kk < 4; ++kk) {
        int lin = kk * 256 + tid;
        int ty = lin >> 5, tx = lin & 31;
        int cy = ty + 4, cx = tx + 4;
        int gy = y0 + ty, gx = x0 + tx;

        float bmm = sB[cy-1][cx-1], bm0 = sB[cy-1][cx], bmp = sB[cy-1][cx+1];
        float b0m = sB[cy  ][cx-1], b00 = sB[cy  ][cx], b0p = sB[cy  ][cx+1];
        float bpm = sB[cy+1][cx-1], bp0 = sB[cy+1][cx], bpp = sB[cy+1][cx+1];

        float2 gg = sGG[ty+2][tx+2];
        float gxv = gg.x, gyv = gg.y;
        float gdm = (-2.f*bmm - bm0 - b0m + b0p + bp0 + 2.f*bpp) * 0.125f;
        float gda = (bm0 + 2.f*bmp - b0m + b0p - 2.f*bpm - bp0) * 0.125f;
        float lap = bm0 + b0m - 4.f*b00 + b0p + bp0;
        float hxx = b0m - 2.f*b00 + b0p;
        float hyy = bm0 - 2.f*b00 + bp0;
        float hxy = (bmm - bmp - bpm + bpp) * 0.25f;
        float gcross = 0.25f * (bm0 + b0m + b0p + bp0);
        float hf = ((bmm + bmp + bpm + bpp) - 2.f*(bm0 + b0m + b0p + bp0) + 4.f*b00) * 0.0625f;

        float grad_mag = sqrtf(gxv*gxv + gyv*gyv + EPS_);
        float hm = 0.5f * (hxx + hyy);
        float hsd = 0.5f * (hxx - hyy);
        float hs = sqrtf(hsd*hsd + hxy*hxy + EPS_);
        float lam_max = hm + hs, lam_min = hm - hs;

        float md  = 0.25f * (gxv + gyv + gdm + gda);
        float m2d = 0.25f * (gxv*gxv + gyv*gyv + gdm*gdm + gda*gda);
        float dir_var = m2d - md * md;

        // 10 unique 5x5 convs on bayer
        float s5[10];
        #pragma unroll
        for (int q = 0; q < 10; ++q) s5[q] = 0.f;
        #pragma unroll
        for (int dy = 0; dy < 5; ++dy) {
            #pragma unroll
            for (int dx = 0; dx < 5; ++dx) {
                float v = sB[cy + dy - 2][cx + dx - 2];
                int widx = dy * 5 + dx;
                #pragma unroll
                for (int q = 0; q < 10; ++q) s5[q] = fmaf(sK5[q * 25 + widx], v, s5[q]);
            }
        }

        float gh = 0.5f*(b0m + b00 + b0p) - 0.25f*(sB[cy][cx-2] + sB[cy][cx+2]);
        float gv = 0.5f*(bm0 + b00 + bp0) - 0.25f*(sB[cy-2][cx] + sB[cy+2][cx]);
        float dgc = fabsf(gh - gv);

        // J (smooth5 of gx/gy products) + cdv (box5 moments of rg/bg) — direct taps
        float jxx=0.f, jyy=0.f, jxy=0.f, m1r=0.f, m2r=0.f, m1b=0.f, m2b=0.f;
        #pragma unroll
        for (int dy = 0; dy < 5; ++dy) {
            float wy = w5[dy];
            #pragma unroll
            for (int dx = 0; dx < 5; ++dx) {
                float w = wy * w5[dx];
                float2 ab = sGG[ty + dy][tx + dx];
                jxx = fmaf(w, ab.x * ab.x, jxx);
                jyy = fmaf(w, ab.y * ab.y, jyy);
                jxy = fmaf(w, ab.x * ab.y, jxy);
                float2 cd = sCD[ty + dy][tx + dx];
                m1r += cd.x; m2r = fmaf(cd.x, cd.x, m2r);
                m1b += cd.y; m2b = fmaf(cd.y, cd.y, m2b);
            }
        }
        const float inv81 = 1.f / 81.f;
        jxx *= inv81; jyy *= inv81; jxy *= inv81;
        float jd = 0.5f * (jxx - jyy);
        float aniso = 2.f * sqrtf(jd*jd + jxy*jxy + EPS_) / (jxx + jyy + EPS_);
        const float inv25 = 0.04f;
        m1r *= inv25; m2r *= inv25; m1b *= inv25; m2b *= inv25;
        float var_r = fmaxf(m2r - m1r*m1r, 0.f);
        float var_b = fmaxf(m2b - m1b*m1b, 0.f);
        float cdv = var_r + var_b;

        float2 cdc = sCD[ty+2][tx+2];
        float rg  = cdc.x;
        float bgv = cdc.y;
        float gpd = sGPD[ty][tx];
        float chroma = sqrtf(rg*rg + bgv*bgv + EPS_);

        int p_r = gy & 1, p_c = gx & 1;
        float r_m = (p_r == 1 && p_c == 0) ? 1.f : 0.f;
        float b_m = (p_r == 0 && p_c == 1) ? 1.f : 0.f;
        float g_m = (p_r == p_c) ? 1.f : 0.f;
        float gir = (p_r == p_c) ? (b00 - gcross) : 0.f;

        float orient_e = sqrtf(s5[7]*s5[7] + s5[8]*s5[8] + EPS_);
        float cb_e     = fabsf(s5[0]);
        float phase_e  = sqrtf(s5[5]*s5[5] + s5[6]*s5[6] + EPS_);
        float highband = sqrtf(s5[9]*s5[9] + hf*hf + EPS_);

        float* p = outb + (size_t)gy * W_ + gx;
        __builtin_nontemporal_store(gxv,      p +  0*HW);
        __builtin_nontemporal_store(gyv,      p +  1*HW);
        __builtin_nontemporal_store(gdm,      p +  2*HW);
        __builtin_nontemporal_store(gda,      p +  3*HW);
        __builtin_nontemporal_store(grad_mag, p +  4*HW);
        __builtin_nontemporal_store(lap,      p +  5*HW);
        __builtin_nontemporal_store(lam_max,  p +  6*HW);
        __builtin_nontemporal_store(lam_min,  p +  7*HW);
        __builtin_nontemporal_store(aniso,    p +  8*HW);
        __builtin_nontemporal_store(dir_var,  p +  9*HW);
        __builtin_nontemporal_store(orient_e, p + 10*HW);
        __builtin_nontemporal_store(r_m,      p + 11*HW);
        __builtin_nontemporal_store(g_m,      p + 12*HW);
        __builtin_nontemporal_store(b_m,      p + 13*HW);
        __builtin_nontemporal_store(gpd,      p + 14*HW);
        __builtin_nontemporal_store(rg,       p + 15*HW);
        __builtin_nontemporal_store(bgv,      p + 16*HW);
        __builtin_nontemporal_store(gir,      p + 17*HW);
        __builtin_nontemporal_store(dgc,      p + 18*HW);
        __builtin_nontemporal_store(chroma,   p + 19*HW);
        __builtin_nontemporal_store(cdv,      p + 20*HW);
        __builtin_nontemporal_store(cb_e,     p + 21*HW);
        __builtin_nontemporal_store(s5[1],    p + 22*HW);
        __builtin_nontemporal_store(s5[2],    p + 23*HW);
        __builtin_nontemporal_store(s5[1],    p + 24*HW);
        __builtin_nontemporal_store(s5[2],    p + 25*HW);
        __builtin_nontemporal_store(phase_e,  p + 26*HW);
        __builtin_nontemporal_store(s5[3],    p + 27*HW);
        __builtin_nontemporal_store(s5[4],    p + 28*HW);
        __builtin_nontemporal_store(highband, p + 29*HW);
    }
}

extern "C" void kernel_launch(void* const* d_in, const int* in_sizes, int n_in,
                              void* d_out, int out_size, void* d_ws, size_t ws_size,
                              hipStream_t stream) {
    const float* bayer = (const float*)d_in[0];
    float* out = (float*)d_out;
    (void)in_sizes; (void)n_in; (void)out_size; (void)d_ws; (void)ws_size;

    init_k5_kernel<<<dim3(1), dim3(64), 0, stream>>>();
    dim3 grid(W_ / TILE, H_ / TILE, 4);
    bayer_feat_kernel<<<grid, dim3(256), 0, stream>>>(bayer, out);
}

// Round 3
// 97.364 us; speedup vs baseline: 10.7449x; 1.6305x over previous
//
#include <hip/hip_runtime.h>
#include <math.h>

#define H_ 768
#define W_ 768
#define TILE 32
#define EXT 36     // TILE + 4
#define BH 40      // TILE + 8
#define EPS_ 1e-6f

__device__ float g_k5bank[250];

__global__ void init_k5_kernel() {
    int k = threadIdx.x;
    if (k >= 10) return;
    double raw[25];
    const double PI = 3.14159265358979323846;
    for (int i = 0; i < 5; ++i) {
        for (int j = 0; j < 5; ++j) {
            double v = 0.0;
            switch (k) {
                case 0: v = ((i + j) & 1) ? -1.0 : 1.0; break;
                case 1: v = (j & 1) ? -1.0 : 1.0; break;
                case 2: v = (i & 1) ? -1.0 : 1.0; break;
                case 3: v = sin(2.0 * PI * j / 5.0); break;
                case 4: v = sin(2.0 * PI * i / 5.0); break;
                case 5: v = cos(2.0 * PI * j / 5.0); break;
                case 6: v = cos(2.0 * PI * i / 5.0); break;
                case 7:
                case 8: {
                    double theta = (k == 7) ? PI / 4.0 : 3.0 * PI / 4.0;
                    double y = (double)(i - 2), x = (double)(j - 2);
                    double ct = cos(theta), st = sin(theta);
                    double xt = x * ct + y * st;
                    double yt = -x * st + y * ct;
                    double env = exp(-(xt * xt + 0.4225 * yt * yt) / (2.0 * 1.1 * 1.1));
                    v = env * cos(2.0 * PI * xt / 3.0);
                } break;
                case 9: v = cos(PI * (i + 0.5) * 2.0 / 5.0) * cos(PI * (j + 0.5) * 2.0 / 5.0); break;
            }
            raw[i * 5 + j] = v;
        }
    }
    double mean = 0.0;
    for (int i = 0; i < 25; ++i) mean += raw[i];
    mean /= 25.0;
    double s = 0.0;
    for (int i = 0; i < 25; ++i) { raw[i] -= mean; s += fabs(raw[i]); }
    if (s < 1e-6) s = 1e-6;
    for (int i = 0; i < 25; ++i) g_k5bank[k * 25 + i] = (float)(raw[i] / s);
}

__device__ __forceinline__ int refl(int i, int n) {
    i = (i < 0) ? -i : i;
    return (i >= n) ? (2 * n - 2 - i) : i;
}

// LDS overlay (54272 B = 106 x 512):
//  [0,10368)      sGG  float2[36*36]   (gx,gy)        phases 2-5
//  [10368,20736)  sCD  float2[36*36]   (rg,bg)        phases 2-5
//  [20736,27136)  sB   float [40*40]                  phases 1-3
//  [27136,31232)  sGPD float [32*32]                  phases 2-3
//  [31232,49664)  sV4  float4[32*36]   (Vo,Va,Vs,Vc)  phases 2-3
//  [49664,54272)  sVd  float [32*36]                  phases 2-3
//  overlay B (phases 4-5, after sync):
//  [20736,29952)  sVJ2 float2[32*36]   (jxx_v,jyy_v)
//  [29952,34560)  sVJ1 float [32*36]   jxy_v
//  [34560,52992)  sVM  float4[32*36]   (m1r,m2r,m1b,m2b)

__global__ __launch_bounds__(256, 3)
void bayer_feat_kernel(const float* __restrict__ in, float* __restrict__ out) {
    __shared__ __align__(16) char smem[54272];
    float2* const sGG  = (float2*)(smem);
    float2* const sCD  = (float2*)(smem + 10368);
    float*  const sB   = (float*) (smem + 20736);
    float*  const sGPD = (float*) (smem + 27136);
    float4* const sV4  = (float4*)(smem + 31232);
    float*  const sVd  = (float*) (smem + 49664);
    float2* const sVJ2 = (float2*)(smem + 20736);
    float*  const sVJ1 = (float*) (smem + 29952);
    float4* const sVM  = (float4*)(smem + 34560);

    const int tid = threadIdx.x;
    const int x0 = blockIdx.x * TILE;
    const int y0 = blockIdx.y * TILE;
    const int bz = blockIdx.z;
    const float* __restrict__ inb = in + (size_t)bz * H_ * W_;

    // ---- phase 1: bayer tile + halo 4 (reflect) ----
    for (int i = tid; i < BH * BH; i += 256) {
        int iy = i / BH, ix = i - iy * BH;
        sB[i] = inb[refl(y0 - 4 + iy, H_) * W_ + refl(x0 - 4 + ix, W_)];
    }
    __syncthreads();

    const float w5c[5] = {1.f, 2.f, 3.f, 2.f, 1.f};

    // ---- phase 2a: ext 36x36 -> gx/gy, rg/bg, gpd (reflect-at-fill) ----
    for (int i = tid; i < EXT * EXT; i += 256) {
        int ey = i / EXT, ex = i - ey * EXT;
        int gyi = y0 - 2 + ey, gxi = x0 - 2 + ex;
        int py = refl(gyi, H_), pxc = refl(gxi, W_);
        int ry = py - (y0 - 4), rx = pxc - (x0 - 4);

        float bmm = sB[(ry-1)*BH + rx-1], bm0 = sB[(ry-1)*BH + rx], bmp = sB[(ry-1)*BH + rx+1];
        float b0m = sB[ ry   *BH + rx-1],                            b0p = sB[ ry   *BH + rx+1];
        float bpm = sB[(ry+1)*BH + rx-1], bp0 = sB[(ry+1)*BH + rx], bpp = sB[(ry+1)*BH + rx+1];
        float gxval = ((bmp - bmm) + 2.f*(b0p - b0m) + (bpp - bpm)) * 0.125f;
        float gyval = ((bpm - bmm) + 2.f*(bp0 - bm0) + (bpp - bmp)) * 0.125f;
        sGG[i] = make_float2(gxval, gyval);

        int p_r = py & 1, p_c = pxc & 1;
        float A0 = 0.f, A1 = 0.f, B0 = 0.f, B1 = 0.f;
        #pragma unroll
        for (int dy = 0; dy < 5; ++dy) {
            const float* row = sB + (ry + dy - 2) * BH;
            float cs = row[rx-2] + 3.f*row[rx] + row[rx+2];
            float cd = 2.f*(row[rx-1] + row[rx+1]);
            float wy = w5c[dy];
            if (dy & 1) { B0 += wy * cs; B1 += wy * cd; }
            else        { A0 += wy * cs; A1 += wy * cd; }
        }
        float rA0 = p_r ? B0 : A0;
        float rA1 = p_r ? B1 : A1;
        float rB0 = p_r ? A0 : B0;
        float rB1 = p_r ? A1 : B1;
        float n_gb = p_c ? rA1 : rA0;
        float n_b  = p_c ? rA0 : rA1;
        float n_r  = p_c ? rB1 : rB0;
        float n_gr = p_c ? rB0 : rB1;

        float inv_r  = p_r ? (p_c ? 0.05f   : 0.04f)   : (p_c ? 0.0625f : 0.05f);
        float inv_b  = p_r ? (p_c ? 0.05f   : 0.0625f) : (p_c ? 0.04f   : 0.05f);
        float inv_gr = p_r ? (p_c ? 0.04f   : 0.05f)   : (p_c ? 0.05f   : 0.0625f);
        float inv_gb = p_r ? (p_c ? 0.0625f : 0.05f)   : (p_c ? 0.05f   : 0.04f);
        float inv_g  = (p_r == p_c) ? 0.024390243902439025f : 0.025f;

        float fr  = n_r  * inv_r;
        float fb  = n_b  * inv_b;
        float fgr = n_gr * inv_gr;
        float fgb = n_gb * inv_gb;
        float fg  = (n_gr + n_gb) * inv_g;

        sCD[i] = make_float2(fr - fg, fb - fg);
        if (ey >= 2 && ey < 34 && ex >= 2 && ex < 34)
            sGPD[(ey - 2) * 32 + (ex - 2)] = fgr - fgb;
    }

    // ---- phase 2b: vertical 5-tap profile sums over [32 rows][36 cols] ----
    for (int i = tid; i < 32 * 36; i += 256) {
        int ty = i / 36, ex = i - ty * 36;
        const float* col = sB + (ty + 2) * BH + ex + 2;
        float v0 = col[0], v1 = col[BH], v2 = col[2*BH], v3 = col[3*BH], v4 = col[4*BH];
        float Vo = v0 + v1 + v2 + v3 + v4;
        float Va = v0 - v1 + v2 - v3 + v4;
        float Vs = 0.95105651629515f*(v1 - v4) + 0.58778525229247f*(v2 - v3);
        float Vc = v0 + 0.30901699437495f*(v1 + v4) - 0.80901699437495f*(v2 + v3);
        float Vd = 0.80901699437495f*(v0 + v4) - 0.30901699437495f*(v1 + v3) - v2;
        sV4[i] = make_float4(Vo, Va, Vs, Vc);
        sVd[i] = Vd;
    }
    __syncthreads();

    const size_t HW = (size_t)H_ * W_;
    float* __restrict__ outb = out + (size_t)bz * 30 * HW;
    const float* gwp = g_k5bank + 175;   // normalized gabor45; g135 = column mirror

    // ---- phase 3: per-pixel, everything except aniso/cdv (28 channels) ----
    #pragma unroll 1
    for (int kk = 0; kk < 4; ++kk) {
        int lin = kk * 256 + tid;
        int ty = lin >> 5, tx = lin & 31;
        int cy = ty + 4, cx = tx + 4;
        int gy = y0 + ty, gx = x0 + tx;

        float t[5][5];
        #pragma unroll
        for (int dy = 0; dy < 5; ++dy)
            #pragma unroll
            for (int dx = 0; dx < 5; ++dx)
                t[dy][dx] = sB[(cy + dy - 2) * BH + (cx + dx - 2)];

        float bmm = t[1][1], bm0 = t[1][2], bmp = t[1][3];
        float b0m = t[2][1], b00 = t[2][2], b0p = t[2][3];
        float bpm = t[3][1], bp0 = t[3][2], bpp = t[3][3];

        float2 gg = sGG[(ty + 2) * 36 + tx + 2];
        float gxv = gg.x, gyv = gg.y;
        float gdm = (-2.f*bmm - bm0 - b0m + b0p + bp0 + 2.f*bpp) * 0.125f;
        float gda = (bm0 + 2.f*bmp - b0m + b0p - 2.f*bpm - bp0) * 0.125f;
        float lap = bm0 + b0m - 4.f*b00 + b0p + bp0;
        float hxx = b0m - 2.f*b00 + b0p;
        float hyy = bm0 - 2.f*b00 + bp0;
        float hxy = (bmm - bmp - bpm + bpp) * 0.25f;
        float gcross = 0.25f * (bm0 + b0m + b0p + bp0);
        float hf = ((bmm + bmp + bpm + bpp) - 2.f*(bm0 + b0m + b0p + bp0) + 4.f*b00) * 0.0625f;

        float grad_mag = sqrtf(gxv*gxv + gyv*gyv + EPS_);
        float hm = 0.5f * (hxx + hyy);
        float hsd = 0.5f * (hxx - hyy);
        float hs = sqrtf(hsd*hsd + hxy*hxy + EPS_);
        float lam_max = hm + hs, lam_min = hm - hs;

        float md  = 0.25f * (gxv + gyv + gdm + gda);
        float m2d = 0.25f * (gxv*gxv + gyv*gyv + gdm*gdm + gda*gda);
        float dir_var = m2d - md * md;

        // gabors (direct, shared taps, mirrored for g135)
        float g45 = 0.f, g135 = 0.f;
        #pragma unroll
        for (int dy = 0; dy < 5; ++dy) {
            #pragma unroll
            for (int dx = 0; dx < 5; ++dx) {
                float w = gwp[dy * 5 + dx];
                g45  = fmaf(w, t[dy][dx],     g45);
                g135 = fmaf(w, t[dy][4 - dx], g135);
            }
        }

        // separable 5x5 bank: horizontal combines of vertical sums
        int vb = ty * 36 + tx;
        float4 q0 = sV4[vb], q1 = sV4[vb+1], q2 = sV4[vb+2], q3 = sV4[vb+3], q4 = sV4[vb+4];
        float d0 = sVd[vb], d1 = sVd[vb+1], d2 = sVd[vb+2], d3 = sVd[vb+3], d4 = sVd[vb+4];

        float box  = q0.x + q1.x + q2.x + q3.x + q4.x;
        float shr  = q0.x - q1.x + q2.x - q3.x + q4.x;
        float sxr  = 0.95105651629515f*(q1.x - q4.x) + 0.58778525229247f*(q2.x - q3.x);
        float pxr  = q0.x + 0.30901699437495f*(q1.x + q4.x) - 0.80901699437495f*(q2.x + q3.x);
        float cbr  = q0.y - q1.y + q2.y - q3.y + q4.y;
        float svr  = q0.y + q1.y + q2.y + q3.y + q4.y;
        float syr  = q0.z + q1.z + q2.z + q3.z + q4.z;
        float pyr  = q0.w + q1.w + q2.w + q3.w + q4.w;
        float dctr = 0.80901699437495f*(d0 + d4) - 0.30901699437495f*(d1 + d3) - d2;

        float cb_n = (cbr - 0.04f * box) * 0.04006410256410f;
        float sh_n = (shr - 0.2f  * box) * 0.04166666666667f;
        float sv_n = (svr - 0.2f  * box) * 0.04166666666667f;
        float sx_n = sxr * 0.06498394f;
        float sy_n = syr * 0.06498394f;
        float px_n = pxr * 0.06180339887f;
        float py_n = pyr * 0.06180339887f;
        float dct_n = dctr * 0.09549150281f;

        float gh = 0.5f*(t[2][1] + t[2][2] + t[2][3]) - 0.25f*(t[2][0] + t[2][4]);
        float gv = 0.5f*(t[1][2] + t[2][2] + t[3][2]) - 0.25f*(t[0][2] + t[4][2]);
        float dgc = fabsf(gh - gv);

        float2 cdc = sCD[(ty + 2) * 36 + tx + 2];
        float rg  = cdc.x;
        float bgv = cdc.y;
        float gpd = sGPD[ty * 32 + tx];
        float chroma = sqrtf(rg*rg + bgv*bgv + EPS_);

        int p_r = gy & 1, p_c = gx & 1;
        float r_m = (p_r == 1 && p_c == 0) ? 1.f : 0.f;
        float b_m = (p_r == 0 && p_c == 1) ? 1.f : 0.f;
        float g_m = (p_r == p_c) ? 1.f : 0.f;
        float gir = (p_r == p_c) ? (b00 - gcross) : 0.f;

        float orient_e = sqrtf(g45*g45 + g135*g135 + EPS_);
        float cb_e     = fabsf(cb_n);
        float phase_e  = sqrtf(px_n*px_n + py_n*py_n + EPS_);
        float highband = sqrtf(dct_n*dct_n + hf*hf + EPS_);

        float* p = outb + (size_t)gy * W_ + gx;
        __builtin_nontemporal_store(gxv,      p +  0*HW);
        __builtin_nontemporal_store(gyv,      p +  1*HW);
        __builtin_nontemporal_store(gdm,      p +  2*HW);
        __builtin_nontemporal_store(gda,      p +  3*HW);
        __builtin_nontemporal_store(grad_mag, p +  4*HW);
        __builtin_nontemporal_store(lap,      p +  5*HW);
        __builtin_nontemporal_store(lam_max,  p +  6*HW);
        __builtin_nontemporal_store(lam_min,  p +  7*HW);
        __builtin_nontemporal_store(dir_var,  p +  9*HW);
        __builtin_nontemporal_store(orient_e, p + 10*HW);
        __builtin_nontemporal_store(r_m,      p + 11*HW);
        __builtin_nontemporal_store(g_m,      p + 12*HW);
        __builtin_nontemporal_store(b_m,      p + 13*HW);
        __builtin_nontemporal_store(gpd,      p + 14*HW);
        __builtin_nontemporal_store(rg,       p + 15*HW);
        __builtin_nontemporal_store(bgv,      p + 16*HW);
        __builtin_nontemporal_store(gir,      p + 17*HW);
        __builtin_nontemporal_store(dgc,      p + 18*HW);
        __builtin_nontemporal_store(chroma,   p + 19*HW);
        __builtin_nontemporal_store(cb_e,     p + 21*HW);
        __builtin_nontemporal_store(sh_n,     p + 22*HW);
        __builtin_nontemporal_store(sv_n,     p + 23*HW);
        __builtin_nontemporal_store(sh_n,     p + 24*HW);
        __builtin_nontemporal_store(sv_n,     p + 25*HW);
        __builtin_nontemporal_store(phase_e,  p + 26*HW);
        __builtin_nontemporal_store(sx_n,     p + 27*HW);
        __builtin_nontemporal_store(sy_n,     p + 28*HW);
        __builtin_nontemporal_store(highband, p + 29*HW);
    }
    __syncthreads();   // before overwriting sB/sGPD/sV4/sVd with overlay B

    // ---- phase 4: vertical sums for J (smooth5) and chroma moments (box5) ----
    for (int i = tid; i < 32 * 36; i += 256) {
        int ty = i / 36, ex = i - ty * 36;
        float jxxv = 0.f, jyyv = 0.f, jxyv = 0.f;
        float s1r = 0.f, s2r = 0.f, s1b = 0.f, s2b = 0.f;
        #pragma unroll
        for (int dy = 0; dy < 5; ++dy) {
            float w = w5c[dy];
            float2 g = sGG[(ty + dy) * 36 + ex];
            jxxv = fmaf(w, g.x * g.x, jxxv);
            jyyv = fmaf(w, g.y * g.y, jyyv);
            jxyv = fmaf(w, g.x * g.y, jxyv);
            float2 cd = sCD[(ty + dy) * 36 + ex];
            s1r += cd.x; s2r = fmaf(cd.x, cd.x, s2r);
            s1b += cd.y; s2b = fmaf(cd.y, cd.y, s2b);
        }
        sVJ2[i] = make_float2(jxxv, jyyv);
        sVJ1[i] = jxyv;
        sVM[i]  = make_float4(s1r, s2r, s1b, s2b);
    }
    __syncthreads();

    // ---- phase 5: horizontal combine -> aniso (ch 8), cdv (ch 20) ----
    #pragma unroll 1
    for (int kk = 0; kk < 4; ++kk) {
        int lin = kk * 256 + tid;
        int ty = lin >> 5, tx = lin & 31;
        int gy = y0 + ty, gx = x0 + tx;
        int b = ty * 36 + tx;

        float2 a0 = sVJ2[b], a1 = sVJ2[b+1], a2 = sVJ2[b+2], a3 = sVJ2[b+3], a4 = sVJ2[b+4];
        float  c0 = sVJ1[b], c1 = sVJ1[b+1], c2 = sVJ1[b+2], c3 = sVJ1[b+3], c4 = sVJ1[b+4];
        float4 v0 = sVM[b],  v1 = sVM[b+1],  v2 = sVM[b+2],  v3 = sVM[b+3],  v4 = sVM[b+4];

        float jxx = a0.x + 2.f*a1.x + 3.f*a2.x + 2.f*a3.x + a4.x;
        float jyy = a0.y + 2.f*a1.y + 3.f*a2.y + 2.f*a3.y + a4.y;
        float jxy = c0 + 2.f*c1 + 3.f*c2 + 2.f*c3 + c4;
        const float inv81 = 1.f / 81.f;
        jxx *= inv81; jyy *= inv81; jxy *= inv81;
        float jd = 0.5f * (jxx - jyy);
        float aniso = 2.f * sqrtf(jd*jd + jxy*jxy + EPS_) / (jxx + jyy + EPS_);

        const float inv25 = 0.04f;
        float m1r = (v0.x + v1.x + v2.x + v3.x + v4.x) * inv25;
        float m2r = (v0.y + v1.y + v2.y + v3.y + v4.y) * inv25;
        float m1b = (v0.z + v1.z + v2.z + v3.z + v4.z) * inv25;
        float m2b = (v0.w + v1.w + v2.w + v3.w + v4.w) * inv25;
        float var_r = fmaxf(m2r - m1r*m1r, 0.f);
        float var_b = fmaxf(m2b - m1b*m1b, 0.f);
        float cdv = var_r + var_b;

        float* p = outb + (size_t)gy * W_ + gx;
        __builtin_nontemporal_store(aniso, p +  8*HW);
        __builtin_nontemporal_store(cdv,   p + 20*HW);
    }
}

extern "C" void kernel_launch(void* const* d_in, const int* in_sizes, int n_in,
                              void* d_out, int out_size, void* d_ws, size_t ws_size,
                              hipStream_t stream) {
    const float* bayer = (const float*)d_in[0];
    float* out = (float*)d_out;
    (void)in_sizes; (void)n_in; (void)out_size; (void)d_ws; (void)ws_size;

    init_k5_kernel<<<dim3(1), dim3(64), 0, stream>>>();
    dim3 grid(W_ / TILE, H_ / TILE, 4);
    bayer_feat_kernel<<<grid, dim3(256), 0, stream>>>(bayer, out);
}

// Round 5
// 86.940 us; speedup vs baseline: 12.0332x; 1.1199x over previous
//
#include <hip/hip_runtime.h>
#include <math.h>

#define H_ 768
#define W_ 768
#define TILE 32
#define EXT 36
#define BROW 44   // sBp row stride: 2 left-pad + 40 data + 2 slack (16B-aligned rows)
#define EPS_ 1e-6f

typedef float vfloat4 __attribute__((ext_vector_type(4)));
typedef float vfloat2 __attribute__((ext_vector_type(2)));

__device__ float g_k5bank[250];

__global__ void init_k5_kernel() {
    int k = threadIdx.x;
    if (k >= 10) return;
    double raw[25];
    const double PI = 3.14159265358979323846;
    for (int i = 0; i < 5; ++i) {
        for (int j = 0; j < 5; ++j) {
            double v = 0.0;
            switch (k) {
                case 0: v = ((i + j) & 1) ? -1.0 : 1.0; break;
                case 1: v = (j & 1) ? -1.0 : 1.0; break;
                case 2: v = (i & 1) ? -1.0 : 1.0; break;
                case 3: v = sin(2.0 * PI * j / 5.0); break;
                case 4: v = sin(2.0 * PI * i / 5.0); break;
                case 5: v = cos(2.0 * PI * j / 5.0); break;
                case 6: v = cos(2.0 * PI * i / 5.0); break;
                case 7:
                case 8: {
                    double theta = (k == 7) ? PI / 4.0 : 3.0 * PI / 4.0;
                    double y = (double)(i - 2), x = (double)(j - 2);
                    double ct = cos(theta), st = sin(theta);
                    double xt = x * ct + y * st;
                    double yt = -x * st + y * ct;
                    double env = exp(-(xt * xt + 0.4225 * yt * yt) / (2.0 * 1.1 * 1.1));
                    v = env * cos(2.0 * PI * xt / 3.0);
                } break;
                case 9: v = cos(PI * (i + 0.5) * 2.0 / 5.0) * cos(PI * (j + 0.5) * 2.0 / 5.0); break;
            }
            raw[i * 5 + j] = v;
        }
    }
    double mean = 0.0;
    for (int i = 0; i < 25; ++i) mean += raw[i];
    mean /= 25.0;
    double s = 0.0;
    for (int i = 0; i < 25; ++i) { raw[i] -= mean; s += fabs(raw[i]); }
    if (s < 1e-6) s = 1e-6;
    for (int i = 0; i < 25; ++i) g_k5bank[k * 25 + i] = (float)(raw[i] / s);
}

__device__ __forceinline__ int refl(int i, int n) {
    i = (i < 0) ? -i : i;
    return (i >= n) ? (2 * n - 2 - i) : i;
}

// LDS layout (52992 B total -> 3 blocks/CU):
//  sGG  [0,10368)      float2[36*36] (gx,gy)       phases 2-4
//  sCD  [10368,20736)  float2[36*36] (rg,bg)       phases 2-4
//  sBp  [20736,27776)  float[40*44]  bayer,+2 col  phases 1-3
//  sGPD [27776,31872)  float[32*32]                phases 2-3
//  overlay (written phase 4, after phase 3 done with sBp/sGPD):
//  sVJ2 [20736,29952)  float2[32*36] (jxx_v,jyy_v)
//  sVJ1 [29952,34560)  float[32*36]  jxy_v
//  sVM  [34560,52992)  float4[32*36] (m1r,m2r,m1b,m2b)

#define STORE4(ch, a) do { \
    vfloat4 _v = { (a)[0], (a)[1], (a)[2], (a)[3] }; \
    __builtin_nontemporal_store(_v, (vfloat4*)(p + (size_t)(ch) * HW)); \
} while (0)

__global__ __launch_bounds__(256, 3)
void bayer_feat_kernel(const float* __restrict__ in, float* __restrict__ out) {
    __shared__ __align__(16) char smem[52992];
    float2* const sGG  = (float2*)(smem);
    float2* const sCD  = (float2*)(smem + 10368);
    float*  const sBp  = (float*) (smem + 20736);
    float*  const sGPD = (float*) (smem + 27776);
    float2* const sVJ2 = (float2*)(smem + 20736);
    float*  const sVJ1 = (float*) (smem + 29952);
    float4* const sVM  = (float4*)(smem + 34560);

    const int tid = threadIdx.x;
    const int x0 = blockIdx.x * TILE;
    const int y0 = blockIdx.y * TILE;
    const int bz = blockIdx.z;
    const float* __restrict__ inb = in + (size_t)bz * H_ * W_;
    const bool border = (x0 == 0) | (x0 + TILE == W_) | (y0 == 0) | (y0 + TILE == H_);

    // ---- phase 1: bayer tile + halo 4 ----
    if (border) {
        for (int i = tid; i < 1600; i += 256) {
            int iy = i / 40, ix = i - iy * 40;
            sBp[iy * BROW + ix + 2] = inb[refl(y0 - 4 + iy, H_) * W_ + refl(x0 - 4 + ix, W_)];
        }
    } else {
        for (int i = tid; i < 1600; i += 256) {
            int iy = i / 40, ix = i - iy * 40;
            sBp[iy * BROW + ix + 2] = inb[(y0 - 4 + iy) * W_ + (x0 - 4 + ix)];
        }
    }
    __syncthreads();

    const float w5c[5] = {1.f, 2.f, 3.f, 2.f, 1.f};

    // ---- phase 2: ext 36x36 -> gx/gy, rg/bg, gpd (reflect-at-fill) ----
    for (int i = tid; i < EXT * EXT; i += 256) {
        int ey = i / EXT, ex = i - ey * EXT;
        int ry, rx, p_r, p_c;
        if (border) {
            int py = refl(y0 - 2 + ey, H_), pxc = refl(x0 - 2 + ex, W_);
            ry = py - (y0 - 4); rx = pxc - (x0 - 4);
            p_r = py & 1; p_c = pxc & 1;
        } else {
            ry = ey + 2; rx = ex + 2;
            p_r = ey & 1; p_c = ex & 1;
        }
        const float* bC = sBp + ry * BROW + rx + 2;

        float bmm = bC[-BROW-1], bm0 = bC[-BROW], bmp = bC[-BROW+1];
        float b0m = bC[-1],                        b0p = bC[1];
        float bpm = bC[BROW-1],  bp0 = bC[BROW],  bpp = bC[BROW+1];
        sGG[i] = make_float2(((bmp - bmm) + 2.f*(b0p - b0m) + (bpp - bpm)) * 0.125f,
                             ((bpm - bmm) + 2.f*(bp0 - bm0) + (bpp - bmp)) * 0.125f);

        float A0 = 0.f, A1 = 0.f, B0 = 0.f, B1 = 0.f;
        #pragma unroll
        for (int dy = 0; dy < 5; ++dy) {
            const float* row = bC + (dy - 2) * BROW;
            float cs = row[-2] + 3.f*row[0] + row[2];
            float cd = 2.f*(row[-1] + row[1]);
            float wy = w5c[dy];
            if (dy & 1) { B0 += wy * cs; B1 += wy * cd; }
            else        { A0 += wy * cs; A1 += wy * cd; }
        }
        float rA0 = p_r ? B0 : A0;
        float rA1 = p_r ? B1 : A1;
        float rB0 = p_r ? A0 : B0;
        float rB1 = p_r ? A1 : B1;
        float n_gb = p_c ? rA1 : rA0;
        float n_b  = p_c ? rA0 : rA1;
        float n_r  = p_c ? rB1 : rB0;
        float n_gr = p_c ? rB0 : rB1;

        float inv_r  = p_r ? (p_c ? 0.05f   : 0.04f)   : (p_c ? 0.0625f : 0.05f);
        float inv_b  = p_r ? (p_c ? 0.05f   : 0.0625f) : (p_c ? 0.04f   : 0.05f);
        float inv_gr = p_r ? (p_c ? 0.04f   : 0.05f)   : (p_c ? 0.05f   : 0.0625f);
        float inv_gb = p_r ? (p_c ? 0.0625f : 0.05f)   : (p_c ? 0.05f   : 0.04f);
        float inv_g  = (p_r == p_c) ? 0.024390243902439025f : 0.025f;

        float fr  = n_r  * inv_r;
        float fb  = n_b  * inv_b;
        float fgr = n_gr * inv_gr;
        float fgb = n_gb * inv_gb;
        float fg  = (n_gr + n_gb) * inv_g;

        sCD[i] = make_float2(fr - fg, fb - fg);
        if (ey >= 2 && ey < 34 && ex >= 2 && ex < 34)
            sGPD[(ey - 2) * 32 + (ex - 2)] = fgr - fgb;
    }
    __syncthreads();

    const size_t HW = (size_t)H_ * W_;
    float* __restrict__ outb = out + (size_t)bz * 30 * HW;
    const float* gwp = g_k5bank + 175;   // gabor45 (normalized); g135 = column mirror

    // ---- phase 3: pixel-quad output, 28 channels ----
    {
        const int ty = tid >> 3;
        const int tx4 = (tid & 7) << 2;
        const int gy = y0 + ty;
        float* p = outb + (size_t)gy * W_ + (x0 + tx4);

        // taps: t[r][c] = bayer(y0+ty-2+r, x0+tx4-2+c), c=0..7
        float t[5][8];
        {
            const int rb = (ty + 2) * BROW + tx4 + 4;
            #pragma unroll
            for (int r = 0; r < 5; ++r) {
                float4 a = *(const float4*)&sBp[rb + r * BROW];
                float4 b = *(const float4*)&sBp[rb + r * BROW + 4];
                t[r][0]=a.x; t[r][1]=a.y; t[r][2]=a.z; t[r][3]=a.w;
                t[r][4]=b.x; t[r][5]=b.y; t[r][6]=b.z; t[r][7]=b.w;
            }
        }

        float gx4[4], gy4[4];
        {
            const float4* q4 = (const float4*)(sGG + (ty + 2) * 36 + tx4 + 2);
            float4 a = q4[0], b = q4[1];
            gx4[0]=a.x; gy4[0]=a.y; gx4[1]=a.z; gy4[1]=a.w;
            gx4[2]=b.x; gy4[2]=b.y; gx4[3]=b.z; gy4[3]=b.w;
        }
        STORE4(0, gx4);
        STORE4(1, gy4);

        float gdm4[4], gda4[4];
        #pragma unroll
        for (int q = 0; q < 4; ++q) {
            float bmm=t[1][q+1], bm0=t[1][q+2], bmp=t[1][q+3];
            float b0m=t[2][q+1],                 b0p=t[2][q+3];
            float bpm=t[3][q+1], bp0=t[3][q+2], bpp=t[3][q+3];
            gdm4[q] = (-2.f*bmm - bm0 - b0m + b0p + bp0 + 2.f*bpp) * 0.125f;
            gda4[q] = (bm0 + 2.f*bmp - b0m + b0p - 2.f*bpm - bp0) * 0.125f;
        }
        STORE4(2, gdm4);
        STORE4(3, gda4);

        {
            float gm4[4];
            #pragma unroll
            for (int q = 0; q < 4; ++q) gm4[q] = sqrtf(gx4[q]*gx4[q] + gy4[q]*gy4[q] + EPS_);
            STORE4(4, gm4);
        }
        {
            float lap4[4], lmx4[4], lmn4[4];
            #pragma unroll
            for (int q = 0; q < 4; ++q) {
                float hxx = t[2][q+1] - 2.f*t[2][q+2] + t[2][q+3];
                float hyy = t[1][q+2] - 2.f*t[2][q+2] + t[3][q+2];
                float hxy = (t[1][q+1] - t[1][q+3] - t[3][q+1] + t[3][q+3]) * 0.25f;
                lap4[q] = hxx + hyy;
                float hm = 0.5f * (hxx + hyy);
                float hsd = 0.5f * (hxx - hyy);
                float hs = sqrtf(hsd*hsd + hxy*hxy + EPS_);
                lmx4[q] = hm + hs; lmn4[q] = hm - hs;
            }
            STORE4(5, lap4); STORE4(6, lmx4); STORE4(7, lmn4);
        }
        {
            float dv4[4];
            #pragma unroll
            for (int q = 0; q < 4; ++q) {
                float md  = 0.25f * (gx4[q] + gy4[q] + gdm4[q] + gda4[q]);
                float m2d = 0.25f * (gx4[q]*gx4[q] + gy4[q]*gy4[q] + gdm4[q]*gdm4[q] + gda4[q]*gda4[q]);
                dv4[q] = m2d - md * md;
            }
            STORE4(9, dv4);
        }

        float hf4[4];
        {
            float gir4[4];
            #pragma unroll
            for (int q = 0; q < 4; ++q) {
                float sumx = t[1][q+2] + t[2][q+1] + t[2][q+3] + t[3][q+2];  // plus-neighbors
                float sumc = t[1][q+1] + t[1][q+3] + t[3][q+1] + t[3][q+3];  // corners
                hf4[q] = (sumc - 2.f*sumx + 4.f*t[2][q+2]) * 0.0625f;
                float gcross = 0.25f * sumx;
                gir4[q] = ((ty & 1) == (q & 1)) ? (t[2][q+2] - gcross) : 0.f;
            }
            STORE4(17, gir4);
        }
        {
            float pr = (float)(ty & 1);
            float rm4[4] = {pr, 0.f, pr, 0.f};
            float bm4[4] = {0.f, 1.f - pr, 0.f, 1.f - pr};
            float gm4[4] = {1.f - pr, pr, 1.f - pr, pr};
            STORE4(11, rm4); STORE4(12, gm4); STORE4(13, bm4);
        }
        {
            float dgc4[4];
            #pragma unroll
            for (int q = 0; q < 4; ++q) {
                float gh = 0.5f*(t[2][q+1] + t[2][q+2] + t[2][q+3]) - 0.25f*(t[2][q] + t[2][q+4]);
                float gv = 0.5f*(t[1][q+2] + t[2][q+2] + t[3][q+2]) - 0.25f*(t[0][q+2] + t[4][q+2]);
                dgc4[q] = fabsf(gh - gv);
            }
            STORE4(18, dgc4);
        }

        // gabors (direct; g135 = column-mirrored weights)
        {
            float g45[4] = {0.f,0.f,0.f,0.f}, g135[4] = {0.f,0.f,0.f,0.f};
            #pragma unroll
            for (int dy = 0; dy < 5; ++dy) {
                #pragma unroll
                for (int dx = 0; dx < 5; ++dx) {
                    float w = gwp[dy * 5 + dx];
                    #pragma unroll
                    for (int q = 0; q < 4; ++q) {
                        g45[q]  = fmaf(w, t[dy][q + dx],     g45[q]);
                        g135[q] = fmaf(w, t[dy][q + 4 - dx], g135[q]);
                    }
                }
            }
            float oe4[4];
            #pragma unroll
            for (int q = 0; q < 4; ++q) oe4[q] = sqrtf(g45[q]*g45[q] + g135[q]*g135[q] + EPS_);
            STORE4(10, oe4);
        }

        // separable 5x5 bank via register column-profiles
        {
            float Vo[8], Va[8], Vs_[8], Vc_[8], Vd_[8];
            #pragma unroll
            for (int c = 0; c < 8; ++c) {
                float v0=t[0][c], v1=t[1][c], v2=t[2][c], v3=t[3][c], v4=t[4][c];
                Vo[c] = v0 + v1 + v2 + v3 + v4;
                Va[c] = v0 - v1 + v2 - v3 + v4;
                Vs_[c] = 0.95105651629515f*(v1 - v4) + 0.58778525229247f*(v2 - v3);
                Vc_[c] = v0 + 0.30901699437495f*(v1 + v4) - 0.80901699437495f*(v2 + v3);
                Vd_[c] = 0.80901699437495f*(v0 + v4) - 0.30901699437495f*(v1 + v3) - v2;
            }
            float cb4[4], sh4[4], sv4[4], sx4[4], sy4[4], ph4[4], hb4[4];
            #pragma unroll
            for (int q = 0; q < 4; ++q) {
                float box = Vo[q] + Vo[q+1] + Vo[q+2] + Vo[q+3] + Vo[q+4];
                float shr = Vo[q] - Vo[q+1] + Vo[q+2] - Vo[q+3] + Vo[q+4];
                float sxr = 0.95105651629515f*(Vo[q+1] - Vo[q+4]) + 0.58778525229247f*(Vo[q+2] - Vo[q+3]);
                float pxr = Vo[q] + 0.30901699437495f*(Vo[q+1] + Vo[q+4]) - 0.80901699437495f*(Vo[q+2] + Vo[q+3]);
                float cbr = Va[q] - Va[q+1] + Va[q+2] - Va[q+3] + Va[q+4];
                float svr = Va[q] + Va[q+1] + Va[q+2] + Va[q+3] + Va[q+4];
                float syr = Vs_[q] + Vs_[q+1] + Vs_[q+2] + Vs_[q+3] + Vs_[q+4];
                float pyr = Vc_[q] + Vc_[q+1] + Vc_[q+2] + Vc_[q+3] + Vc_[q+4];
                float dctr = 0.80901699437495f*(Vd_[q] + Vd_[q+4]) - 0.30901699437495f*(Vd_[q+1] + Vd_[q+3]) - Vd_[q+2];

                cb4[q] = fabsf((cbr - 0.04f * box) * 0.04006410256410f);
                sh4[q] = (shr - 0.2f * box) * 0.04166666666667f;
                sv4[q] = (svr - 0.2f * box) * 0.04166666666667f;
                sx4[q] = sxr * 0.06498394f;
                sy4[q] = syr * 0.06498394f;
                float px_n = pxr * 0.06180339887f;
                float py_n = pyr * 0.06180339887f;
                ph4[q] = sqrtf(px_n*px_n + py_n*py_n + EPS_);
                float dct_n = dctr * 0.09549150281f;
                hb4[q] = sqrtf(dct_n*dct_n + hf4[q]*hf4[q] + EPS_);
            }
            STORE4(21, cb4); STORE4(22, sh4); STORE4(23, sv4);
            STORE4(24, sh4); STORE4(25, sv4); STORE4(26, ph4);
            STORE4(27, sx4); STORE4(28, sy4); STORE4(29, hb4);
        }

        // chroma channels
        {
            const float4* c4 = (const float4*)(sCD + (ty + 2) * 36 + tx4 + 2);
            float4 ca = c4[0], cbv = c4[1];
            float rg4[4] = {ca.x, ca.z, cbv.x, cbv.z};
            float bg4[4] = {ca.y, ca.w, cbv.y, cbv.w};
            STORE4(15, rg4); STORE4(16, bg4);
            float ch4[4];
            #pragma unroll
            for (int q = 0; q < 4; ++q) ch4[q] = sqrtf(rg4[q]*rg4[q] + bg4[q]*bg4[q] + EPS_);
            STORE4(19, ch4);
            float4 gp = *(const float4*)(sGPD + ty * 32 + tx4);
            float gp4[4] = {gp.x, gp.y, gp.z, gp.w};
            STORE4(14, gp4);
        }
    }
    __syncthreads();   // phase 3 done with sBp/sGPD -> overlay write OK

    // ---- phase 4: vertical sums (column pairs) for J + chroma moments ----
    for (int i = tid; i < 576; i += 256) {
        int ty4 = i / 18, e2 = (i - ty4 * 18) * 2;
        float jxx0=0.f,jyy0=0.f,jxy0=0.f, jxx1=0.f,jyy1=0.f,jxy1=0.f;
        float s1r0=0.f,s2r0=0.f,s1b0=0.f,s2b0=0.f, s1r1=0.f,s2r1=0.f,s1b1=0.f,s2b1=0.f;
        #pragma unroll
        for (int dy = 0; dy < 5; ++dy) {
            float w = w5c[dy];
            float4 g = *(const float4*)(sGG + (ty4 + dy) * 36 + e2);
            jxx0 = fmaf(w, g.x*g.x, jxx0); jyy0 = fmaf(w, g.y*g.y, jyy0); jxy0 = fmaf(w, g.x*g.y, jxy0);
            jxx1 = fmaf(w, g.z*g.z, jxx1); jyy1 = fmaf(w, g.w*g.w, jyy1); jxy1 = fmaf(w, g.z*g.w, jxy1);
            float4 c = *(const float4*)(sCD + (ty4 + dy) * 36 + e2);
            s1r0 += c.x; s2r0 = fmaf(c.x, c.x, s2r0); s1b0 += c.y; s2b0 = fmaf(c.y, c.y, s2b0);
            s1r1 += c.z; s2r1 = fmaf(c.z, c.z, s2r1); s1b1 += c.w; s2b1 = fmaf(c.w, c.w, s2b1);
        }
        *(float4*)(sVJ2 + ty4 * 36 + e2) = make_float4(jxx0, jyy0, jxx1, jyy1);
        *(float2*)(sVJ1 + ty4 * 36 + e2) = make_float2(jxy0, jxy1);
        sVM[ty4 * 36 + e2]     = make_float4(s1r0, s2r0, s1b0, s2b0);
        sVM[ty4 * 36 + e2 + 1] = make_float4(s1r1, s2r1, s1b1, s2b1);
    }
    __syncthreads();

    // ---- phase 5: horizontal combine -> aniso (ch 8), cdv (ch 20) ----
    {
        const int ty = tid >> 3;
        const int tx4 = (tid & 7) << 2;
        const int b = ty * 36 + tx4;
        float xx[8], yy[8], xy[8];
        #pragma unroll
        for (int j = 0; j < 8; j += 2) {
            float4 g = *(const float4*)(sVJ2 + b + j);
            xx[j]=g.x; yy[j]=g.y; xx[j+1]=g.z; yy[j+1]=g.w;
        }
        {
            float4 c0 = *(const float4*)(sVJ1 + b);
            float4 c1 = *(const float4*)(sVJ1 + b + 4);
            xy[0]=c0.x; xy[1]=c0.y; xy[2]=c0.z; xy[3]=c0.w;
            xy[4]=c1.x; xy[5]=c1.y; xy[6]=c1.z; xy[7]=c1.w;
        }
        float an4[4], cv4[4];
        const float inv81 = 1.f / 81.f;
        #pragma unroll
        for (int q = 0; q < 4; ++q) {
            float jxx = (xx[q] + 2.f*xx[q+1] + 3.f*xx[q+2] + 2.f*xx[q+3] + xx[q+4]) * inv81;
            float jyy = (yy[q] + 2.f*yy[q+1] + 3.f*yy[q+2] + 2.f*yy[q+3] + yy[q+4]) * inv81;
            float jxy = (xy[q] + 2.f*xy[q+1] + 3.f*xy[q+2] + 2.f*xy[q+3] + xy[q+4]) * inv81;
            float jd = 0.5f * (jxx - jyy);
            an4[q] = 2.f * sqrtf(jd*jd + jxy*jxy + EPS_) / (jxx + jyy + EPS_);
        }
        {
            float4 m0 = sVM[b],   m1 = sVM[b+1], m2 = sVM[b+2], m3 = sVM[b+3];
            float4 m4 = sVM[b+4], m5 = sVM[b+5], m6 = sVM[b+6], m7 = sVM[b+7];
            float4 mm[8] = {m0,m1,m2,m3,m4,m5,m6,m7};
            #pragma unroll
            for (int q = 0; q < 4; ++q) {
                float m1r = (mm[q].x + mm[q+1].x + mm[q+2].x + mm[q+3].x + mm[q+4].x) * 0.04f;
                float m2r = (mm[q].y + mm[q+1].y + mm[q+2].y + mm[q+3].y + mm[q+4].y) * 0.04f;
                float m1b = (mm[q].z + mm[q+1].z + mm[q+2].z + mm[q+3].z + mm[q+4].z) * 0.04f;
                float m2b = (mm[q].w + mm[q+1].w + mm[q+2].w + mm[q+3].w + mm[q+4].w) * 0.04f;
                cv4[q] = fmaxf(m2r - m1r*m1r, 0.f) + fmaxf(m2b - m1b*m1b, 0.f);
            }
        }
        float* p = outb + (size_t)(y0 + ty) * W_ + (x0 + tx4);
        STORE4(8, an4);
        STORE4(20, cv4);
    }
}

extern "C" void kernel_launch(void* const* d_in, const int* in_sizes, int n_in,
                              void* d_out, int out_size, void* d_ws, size_t ws_size,
                              hipStream_t stream) {
    const float* bayer = (const float*)d_in[0];
    float* out = (float*)d_out;
    (void)in_sizes; (void)n_in; (void)out_size; (void)d_ws; (void)ws_size;

    init_k5_kernel<<<dim3(1), dim3(64), 0, stream>>>();
    dim3 grid(W_ / TILE, H_ / TILE, 4);
    bayer_feat_kernel<<<grid, dim3(256), 0, stream>>>(bayer, out);
}

// Round 6
// 83.661 us; speedup vs baseline: 12.5048x; 1.0392x over previous
//
#include <hip/hip_runtime.h>
#include <math.h>

#define H_ 768
#define W_ 768
#define TILE 32
#define EXT 36
#define BROW 44   // sBp row stride: 2 left-pad + 40 data + 2 slack (16B-aligned rows)
#define EPS_ 1e-6f

typedef float vfloat4 __attribute__((ext_vector_type(4)));

__device__ float g_k5bank[250];

__global__ void init_k5_kernel() {
    int k = threadIdx.x;
    if (k >= 10) return;
    double raw[25];
    const double PI = 3.14159265358979323846;
    for (int i = 0; i < 5; ++i) {
        for (int j = 0; j < 5; ++j) {
            double v = 0.0;
            switch (k) {
                case 0: v = ((i + j) & 1) ? -1.0 : 1.0; break;
                case 1: v = (j & 1) ? -1.0 : 1.0; break;
                case 2: v = (i & 1) ? -1.0 : 1.0; break;
                case 3: v = sin(2.0 * PI * j / 5.0); break;
                case 4: v = sin(2.0 * PI * i / 5.0); break;
                case 5: v = cos(2.0 * PI * j / 5.0); break;
                case 6: v = cos(2.0 * PI * i / 5.0); break;
                case 7:
                case 8: {
                    double theta = (k == 7) ? PI / 4.0 : 3.0 * PI / 4.0;
                    double y = (double)(i - 2), x = (double)(j - 2);
                    double ct = cos(theta), st = sin(theta);
                    double xt = x * ct + y * st;
                    double yt = -x * st + y * ct;
                    double env = exp(-(xt * xt + 0.4225 * yt * yt) / (2.0 * 1.1 * 1.1));
                    v = env * cos(2.0 * PI * xt / 3.0);
                } break;
                case 9: v = cos(PI * (i + 0.5) * 2.0 / 5.0) * cos(PI * (j + 0.5) * 2.0 / 5.0); break;
            }
            raw[i * 5 + j] = v;
        }
    }
    double mean = 0.0;
    for (int i = 0; i < 25; ++i) mean += raw[i];
    mean /= 25.0;
    double s = 0.0;
    for (int i = 0; i < 25; ++i) { raw[i] -= mean; s += fabs(raw[i]); }
    if (s < 1e-6) s = 1e-6;
    for (int i = 0; i < 25; ++i) g_k5bank[k * 25 + i] = (float)(raw[i] / s);
}

__device__ __forceinline__ int refl(int i, int n) {
    i = (i < 0) ? -i : i;
    return (i >= n) ? (2 * n - 2 - i) : i;
}

// LDS layout (39168 B total -> 4 blocks/CU LDS-wise):
//  sGG  [0,10368)      float2[36*36] (gx,gy)       phases 2-B
//  sCD  [10368,20736)  float2[36*36] (rg,bg)       phases 2-B
//  sBp  [20736,27776)  float[40*44]  bayer,+2 col  phases 1-3
//  sGPD [27776,31872)  float[32*32]                phases 2-3
//  pass A overlay (after phase 3):
//   sVJ2 [20736,29952) float2[32*36] (jxx_v,jyy_v)
//   sVJ1 [29952,34560) float[32*36]  jxy_v
//  pass B overlay (after pass A):
//   sVM  [20736,39168) float4[32*36] (m1r,m2r,m1b,m2b)

#define STORE4(ch, a) do { \
    vfloat4 _v = { (a)[0], (a)[1], (a)[2], (a)[3] }; \
    *(vfloat4*)(p + (size_t)(ch) * HW) = _v; \
} while (0)

__global__ __launch_bounds__(256, 3)
void bayer_feat_kernel(const float* __restrict__ in, float* __restrict__ out) {
    __shared__ __align__(16) char smem[39168];
    float2* const sGG  = (float2*)(smem);
    float2* const sCD  = (float2*)(smem + 10368);
    float*  const sBp  = (float*) (smem + 20736);
    float*  const sGPD = (float*) (smem + 27776);
    float2* const sVJ2 = (float2*)(smem + 20736);
    float*  const sVJ1 = (float*) (smem + 29952);
    float4* const sVM  = (float4*)(smem + 20736);

    const int tid = threadIdx.x;
    const int x0 = blockIdx.x * TILE;
    const int y0 = blockIdx.y * TILE;
    const int bz = blockIdx.z;
    const float* __restrict__ inb = in + (size_t)bz * H_ * W_;
    const bool border = (x0 == 0) | (x0 + TILE == W_) | (y0 == 0) | (y0 + TILE == H_);

    // ---- phase 1: bayer tile + halo 4 ----
    if (border) {
        for (int i = tid; i < 1600; i += 256) {
            int iy = i / 40, ix = i - iy * 40;
            sBp[iy * BROW + ix + 2] = inb[refl(y0 - 4 + iy, H_) * W_ + refl(x0 - 4 + ix, W_)];
        }
    } else {
        for (int i = tid; i < 1600; i += 256) {
            int iy = i / 40, ix = i - iy * 40;
            sBp[iy * BROW + ix + 2] = inb[(y0 - 4 + iy) * W_ + (x0 - 4 + ix)];
        }
    }
    __syncthreads();

    const float w5c[5] = {1.f, 2.f, 3.f, 2.f, 1.f};

    // ---- phase 2: ext 36x36 -> gx/gy, rg/bg, gpd (reflect-at-fill) ----
    for (int i = tid; i < EXT * EXT; i += 256) {
        int ey = i / EXT, ex = i - ey * EXT;
        int ry, rx, p_r, p_c;
        if (border) {
            int py = refl(y0 - 2 + ey, H_), pxc = refl(x0 - 2 + ex, W_);
            ry = py - (y0 - 4); rx = pxc - (x0 - 4);
            p_r = py & 1; p_c = pxc & 1;
        } else {
            ry = ey + 2; rx = ex + 2;
            p_r = ey & 1; p_c = ex & 1;
        }
        const float* bC = sBp + ry * BROW + rx + 2;

        float bmm = bC[-BROW-1], bm0 = bC[-BROW], bmp = bC[-BROW+1];
        float b0m = bC[-1],                        b0p = bC[1];
        float bpm = bC[BROW-1],  bp0 = bC[BROW],  bpp = bC[BROW+1];
        sGG[i] = make_float2(((bmp - bmm) + 2.f*(b0p - b0m) + (bpp - bpm)) * 0.125f,
                             ((bpm - bmm) + 2.f*(bp0 - bm0) + (bpp - bmp)) * 0.125f);

        float A0 = 0.f, A1 = 0.f, B0 = 0.f, B1 = 0.f;
        #pragma unroll
        for (int dy = 0; dy < 5; ++dy) {
            const float* row = bC + (dy - 2) * BROW;
            float cs = row[-2] + 3.f*row[0] + row[2];
            float cd = 2.f*(row[-1] + row[1]);
            float wy = w5c[dy];
            if (dy & 1) { B0 += wy * cs; B1 += wy * cd; }
            else        { A0 += wy * cs; A1 += wy * cd; }
        }
        float rA0 = p_r ? B0 : A0;
        float rA1 = p_r ? B1 : A1;
        float rB0 = p_r ? A0 : B0;
        float rB1 = p_r ? A1 : B1;
        float n_gb = p_c ? rA1 : rA0;
        float n_b  = p_c ? rA0 : rA1;
        float n_r  = p_c ? rB1 : rB0;
        float n_gr = p_c ? rB0 : rB1;

        float inv_r  = p_r ? (p_c ? 0.05f   : 0.04f)   : (p_c ? 0.0625f : 0.05f);
        float inv_b  = p_r ? (p_c ? 0.05f   : 0.0625f) : (p_c ? 0.04f   : 0.05f);
        float inv_gr = p_r ? (p_c ? 0.04f   : 0.05f)   : (p_c ? 0.05f   : 0.0625f);
        float inv_gb = p_r ? (p_c ? 0.0625f : 0.05f)   : (p_c ? 0.05f   : 0.04f);
        float inv_g  = (p_r == p_c) ? 0.024390243902439025f : 0.025f;

        float fr  = n_r  * inv_r;
        float fb  = n_b  * inv_b;
        float fgr = n_gr * inv_gr;
        float fgb = n_gb * inv_gb;
        float fg  = (n_gr + n_gb) * inv_g;

        sCD[i] = make_float2(fr - fg, fb - fg);
        if (ey >= 2 && ey < 34 && ex >= 2 && ex < 34)
            sGPD[(ey - 2) * 32 + (ex - 2)] = fgr - fgb;
    }
    __syncthreads();

    const size_t HW = (size_t)H_ * W_;
    float* __restrict__ outb = out + (size_t)bz * 30 * HW;
    const float* gwp = g_k5bank + 175;   // gabor45 (normalized); g135 = column mirror

    // ---- phase 3: pixel-quad output, 28 channels ----
    {
        const int ty = tid >> 3;
        const int tx4 = (tid & 7) << 2;
        const int gy = y0 + ty;
        float* p = outb + (size_t)gy * W_ + (x0 + tx4);

        // taps: t[r][c] = bayer(y0+ty-2+r, x0+tx4-2+c), c=0..7
        float t[5][8];
        {
            const int rb = (ty + 2) * BROW + tx4 + 4;
            #pragma unroll
            for (int r = 0; r < 5; ++r) {
                float4 a = *(const float4*)&sBp[rb + r * BROW];
                float4 b = *(const float4*)&sBp[rb + r * BROW + 4];
                t[r][0]=a.x; t[r][1]=a.y; t[r][2]=a.z; t[r][3]=a.w;
                t[r][4]=b.x; t[r][5]=b.y; t[r][6]=b.z; t[r][7]=b.w;
            }
        }

        float gx4[4], gy4[4];
        {
            const float4* q4 = (const float4*)(sGG + (ty + 2) * 36 + tx4 + 2);
            float4 a = q4[0], b = q4[1];
            gx4[0]=a.x; gy4[0]=a.y; gx4[1]=a.z; gy4[1]=a.w;
            gx4[2]=b.x; gy4[2]=b.y; gx4[3]=b.z; gy4[3]=b.w;
        }
        STORE4(0, gx4);
        STORE4(1, gy4);

        float gdm4[4], gda4[4];
        #pragma unroll
        for (int q = 0; q < 4; ++q) {
            float bmm=t[1][q+1], bm0=t[1][q+2], bmp=t[1][q+3];
            float b0m=t[2][q+1],                 b0p=t[2][q+3];
            float bpm=t[3][q+1], bp0=t[3][q+2], bpp=t[3][q+3];
            gdm4[q] = (-2.f*bmm - bm0 - b0m + b0p + bp0 + 2.f*bpp) * 0.125f;
            gda4[q] = (bm0 + 2.f*bmp - b0m + b0p - 2.f*bpm - bp0) * 0.125f;
        }
        STORE4(2, gdm4);
        STORE4(3, gda4);

        {
            float gm4[4];
            #pragma unroll
            for (int q = 0; q < 4; ++q) gm4[q] = sqrtf(gx4[q]*gx4[q] + gy4[q]*gy4[q] + EPS_);
            STORE4(4, gm4);
        }
        {
            float lap4[4], lmx4[4], lmn4[4];
            #pragma unroll
            for (int q = 0; q < 4; ++q) {
                float hxx = t[2][q+1] - 2.f*t[2][q+2] + t[2][q+3];
                float hyy = t[1][q+2] - 2.f*t[2][q+2] + t[3][q+2];
                float hxy = (t[1][q+1] - t[1][q+3] - t[3][q+1] + t[3][q+3]) * 0.25f;
                lap4[q] = hxx + hyy;
                float hm = 0.5f * (hxx + hyy);
                float hsd = 0.5f * (hxx - hyy);
                float hs = sqrtf(hsd*hsd + hxy*hxy + EPS_);
                lmx4[q] = hm + hs; lmn4[q] = hm - hs;
            }
            STORE4(5, lap4); STORE4(6, lmx4); STORE4(7, lmn4);
        }
        {
            float dv4[4];
            #pragma unroll
            for (int q = 0; q < 4; ++q) {
                float md  = 0.25f * (gx4[q] + gy4[q] + gdm4[q] + gda4[q]);
                float m2d = 0.25f * (gx4[q]*gx4[q] + gy4[q]*gy4[q] + gdm4[q]*gdm4[q] + gda4[q]*gda4[q]);
                dv4[q] = m2d - md * md;
            }
            STORE4(9, dv4);
        }

        float hf4[4];
        {
            float gir4[4];
            #pragma unroll
            for (int q = 0; q < 4; ++q) {
                float sumx = t[1][q+2] + t[2][q+1] + t[2][q+3] + t[3][q+2];  // plus-neighbors
                float sumc = t[1][q+1] + t[1][q+3] + t[3][q+1] + t[3][q+3];  // corners
                hf4[q] = (sumc - 2.f*sumx + 4.f*t[2][q+2]) * 0.0625f;
                float gcross = 0.25f * sumx;
                gir4[q] = ((ty & 1) == (q & 1)) ? (t[2][q+2] - gcross) : 0.f;
            }
            STORE4(17, gir4);
        }
        {
            float pr = (float)(ty & 1);
            float rm4[4] = {pr, 0.f, pr, 0.f};
            float bm4[4] = {0.f, 1.f - pr, 0.f, 1.f - pr};
            float gm4[4] = {1.f - pr, pr, 1.f - pr, pr};
            STORE4(11, rm4); STORE4(12, gm4); STORE4(13, bm4);
        }
        {
            float dgc4[4];
            #pragma unroll
            for (int q = 0; q < 4; ++q) {
                float gh = 0.5f*(t[2][q+1] + t[2][q+2] + t[2][q+3]) - 0.25f*(t[2][q] + t[2][q+4]);
                float gv = 0.5f*(t[1][q+2] + t[2][q+2] + t[3][q+2]) - 0.25f*(t[0][q+2] + t[4][q+2]);
                dgc4[q] = fabsf(gh - gv);
            }
            STORE4(18, dgc4);
        }

        // gabors (direct; g135 = column-mirrored weights)
        {
            float g45[4] = {0.f,0.f,0.f,0.f}, g135[4] = {0.f,0.f,0.f,0.f};
            #pragma unroll
            for (int dy = 0; dy < 5; ++dy) {
                #pragma unroll
                for (int dx = 0; dx < 5; ++dx) {
                    float w = gwp[dy * 5 + dx];
                    #pragma unroll
                    for (int q = 0; q < 4; ++q) {
                        g45[q]  = fmaf(w, t[dy][q + dx],     g45[q]);
                        g135[q] = fmaf(w, t[dy][q + 4 - dx], g135[q]);
                    }
                }
            }
            float oe4[4];
            #pragma unroll
            for (int q = 0; q < 4; ++q) oe4[q] = sqrtf(g45[q]*g45[q] + g135[q]*g135[q] + EPS_);
            STORE4(10, oe4);
        }

        // separable 5x5 bank via register column-profiles
        {
            float Vo[8], Va[8], Vs_[8], Vc_[8], Vd_[8];
            #pragma unroll
            for (int c = 0; c < 8; ++c) {
                float v0=t[0][c], v1=t[1][c], v2=t[2][c], v3=t[3][c], v4=t[4][c];
                Vo[c] = v0 + v1 + v2 + v3 + v4;
                Va[c] = v0 - v1 + v2 - v3 + v4;
                Vs_[c] = 0.95105651629515f*(v1 - v4) + 0.58778525229247f*(v2 - v3);
                Vc_[c] = v0 + 0.30901699437495f*(v1 + v4) - 0.80901699437495f*(v2 + v3);
                Vd_[c] = 0.80901699437495f*(v0 + v4) - 0.30901699437495f*(v1 + v3) - v2;
            }
            float cb4[4], sh4[4], sv4[4], sx4[4], sy4[4], ph4[4], hb4[4];
            #pragma unroll
            for (int q = 0; q < 4; ++q) {
                float box = Vo[q] + Vo[q+1] + Vo[q+2] + Vo[q+3] + Vo[q+4];
                float shr = Vo[q] - Vo[q+1] + Vo[q+2] - Vo[q+3] + Vo[q+4];
                float sxr = 0.95105651629515f*(Vo[q+1] - Vo[q+4]) + 0.58778525229247f*(Vo[q+2] - Vo[q+3]);
                float pxr = Vo[q] + 0.30901699437495f*(Vo[q+1] + Vo[q+4]) - 0.80901699437495f*(Vo[q+2] + Vo[q+3]);
                float cbr = Va[q] - Va[q+1] + Va[q+2] - Va[q+3] + Va[q+4];
                float svr = Va[q] + Va[q+1] + Va[q+2] + Va[q+3] + Va[q+4];
                float syr = Vs_[q] + Vs_[q+1] + Vs_[q+2] + Vs_[q+3] + Vs_[q+4];
                float pyr = Vc_[q] + Vc_[q+1] + Vc_[q+2] + Vc_[q+3] + Vc_[q+4];
                float dctr = 0.80901699437495f*(Vd_[q] + Vd_[q+4]) - 0.30901699437495f*(Vd_[q+1] + Vd_[q+3]) - Vd_[q+2];

                cb4[q] = fabsf((cbr - 0.04f * box) * 0.04006410256410f);
                sh4[q] = (shr - 0.2f * box) * 0.04166666666667f;
                sv4[q] = (svr - 0.2f * box) * 0.04166666666667f;
                sx4[q] = sxr * 0.06498394f;
                sy4[q] = syr * 0.06498394f;
                float px_n = pxr * 0.06180339887f;
                float py_n = pyr * 0.06180339887f;
                ph4[q] = sqrtf(px_n*px_n + py_n*py_n + EPS_);
                float dct_n = dctr * 0.09549150281f;
                hb4[q] = sqrtf(dct_n*dct_n + hf4[q]*hf4[q] + EPS_);
            }
            STORE4(21, cb4); STORE4(22, sh4); STORE4(23, sv4);
            STORE4(24, sh4); STORE4(25, sv4); STORE4(26, ph4);
            STORE4(27, sx4); STORE4(28, sy4); STORE4(29, hb4);
        }

        // chroma channels
        {
            const float4* c4 = (const float4*)(sCD + (ty + 2) * 36 + tx4 + 2);
            float4 ca = c4[0], cbv = c4[1];
            float rg4[4] = {ca.x, ca.z, cbv.x, cbv.z};
            float bg4[4] = {ca.y, ca.w, cbv.y, cbv.w};
            STORE4(15, rg4); STORE4(16, bg4);
            float ch4[4];
            #pragma unroll
            for (int q = 0; q < 4; ++q) ch4[q] = sqrtf(rg4[q]*rg4[q] + bg4[q]*bg4[q] + EPS_);
            STORE4(19, ch4);
            float4 gp = *(const float4*)(sGPD + ty * 32 + tx4);
            float gp4[4] = {gp.x, gp.y, gp.z, gp.w};
            STORE4(14, gp4);
        }
    }
    __syncthreads();   // phase 3 done with sBp/sGPD -> overlay write OK

    // ---- pass A1: vertical smooth5 sums of gx/gy products (reads sGG only) ----
    for (int i = tid; i < 576; i += 256) {
        int ty4 = i / 18, e2 = (i - ty4 * 18) * 2;
        float jxx0=0.f,jyy0=0.f,jxy0=0.f, jxx1=0.f,jyy1=0.f,jxy1=0.f;
        #pragma unroll
        for (int dy = 0; dy < 5; ++dy) {
            float w = w5c[dy];
            float4 g = *(const float4*)(sGG + (ty4 + dy) * 36 + e2);
            jxx0 = fmaf(w, g.x*g.x, jxx0); jyy0 = fmaf(w, g.y*g.y, jyy0); jxy0 = fmaf(w, g.x*g.y, jxy0);
            jxx1 = fmaf(w, g.z*g.z, jxx1); jyy1 = fmaf(w, g.w*g.w, jyy1); jxy1 = fmaf(w, g.z*g.w, jxy1);
        }
        *(float4*)(sVJ2 + ty4 * 36 + e2) = make_float4(jxx0, jyy0, jxx1, jyy1);
        *(float2*)(sVJ1 + ty4 * 36 + e2) = make_float2(jxy0, jxy1);
    }
    __syncthreads();

    // ---- pass A2: horizontal combine -> aniso (ch 8) ----
    {
        const int ty = tid >> 3;
        const int tx4 = (tid & 7) << 2;
        const int b = ty * 36 + tx4;
        float xx[8], yy[8], xy[8];
        #pragma unroll
        for (int j = 0; j < 8; j += 2) {
            float4 g = *(const float4*)(sVJ2 + b + j);
            xx[j]=g.x; yy[j]=g.y; xx[j+1]=g.z; yy[j+1]=g.w;
        }
        {
            float4 c0 = *(const float4*)(sVJ1 + b);
            float4 c1 = *(const float4*)(sVJ1 + b + 4);
            xy[0]=c0.x; xy[1]=c0.y; xy[2]=c0.z; xy[3]=c0.w;
            xy[4]=c1.x; xy[5]=c1.y; xy[6]=c1.z; xy[7]=c1.w;
        }
        float an4[4];
        const float inv81 = 1.f / 81.f;
        #pragma unroll
        for (int q = 0; q < 4; ++q) {
            float jxx = (xx[q] + 2.f*xx[q+1] + 3.f*xx[q+2] + 2.f*xx[q+3] + xx[q+4]) * inv81;
            float jyy = (yy[q] + 2.f*yy[q+1] + 3.f*yy[q+2] + 2.f*yy[q+3] + yy[q+4]) * inv81;
            float jxy = (xy[q] + 2.f*xy[q+1] + 3.f*xy[q+2] + 2.f*xy[q+3] + xy[q+4]) * inv81;
            float jd = 0.5f * (jxx - jyy);
            an4[q] = 2.f * sqrtf(jd*jd + jxy*jxy + EPS_) / (jxx + jyy + EPS_);
        }
        float* p = outb + (size_t)(y0 + ty) * W_ + (x0 + tx4);
        STORE4(8, an4);
    }
    __syncthreads();   // pass A done with sVJ2/sVJ1 -> sVM overlay write OK

    // ---- pass B1: vertical box5 moment sums of rg/bg (reads sCD only) ----
    for (int i = tid; i < 576; i += 256) {
        int ty4 = i / 18, e2 = (i - ty4 * 18) * 2;
        float s1r0=0.f,s2r0=0.f,s1b0=0.f,s2b0=0.f, s1r1=0.f,s2r1=0.f,s1b1=0.f,s2b1=0.f;
        #pragma unroll
        for (int dy = 0; dy < 5; ++dy) {
            float4 c = *(const float4*)(sCD + (ty4 + dy) * 36 + e2);
            s1r0 += c.x; s2r0 = fmaf(c.x, c.x, s2r0); s1b0 += c.y; s2b0 = fmaf(c.y, c.y, s2b0);
            s1r1 += c.z; s2r1 = fmaf(c.z, c.z, s2r1); s1b1 += c.w; s2b1 = fmaf(c.w, c.w, s2b1);
        }
        sVM[ty4 * 36 + e2]     = make_float4(s1r0, s2r0, s1b0, s2b0);
        sVM[ty4 * 36 + e2 + 1] = make_float4(s1r1, s2r1, s1b1, s2b1);
    }
    __syncthreads();

    // ---- pass B2: horizontal combine -> cdv (ch 20) ----
    {
        const int ty = tid >> 3;
        const int tx4 = (tid & 7) << 2;
        const int b = ty * 36 + tx4;
        float cv4[4];
        float4 m0 = sVM[b],   m1 = sVM[b+1], m2 = sVM[b+2], m3 = sVM[b+3];
        float4 m4 = sVM[b+4], m5 = sVM[b+5], m6 = sVM[b+6], m7 = sVM[b+7];
        float4 mm[8] = {m0,m1,m2,m3,m4,m5,m6,m7};
        #pragma unroll
        for (int q = 0; q < 4; ++q) {
            float m1r = (mm[q].x + mm[q+1].x + mm[q+2].x + mm[q+3].x + mm[q+4].x) * 0.04f;
            float m2r = (mm[q].y + mm[q+1].y + mm[q+2].y + mm[q+3].y + mm[q+4].y) * 0.04f;
            float m1b = (mm[q].z + mm[q+1].z + mm[q+2].z + mm[q+3].z + mm[q+4].z) * 0.04f;
            float m2b = (mm[q].w + mm[q+1].w + mm[q+2].w + mm[q+3].w + mm[q+4].w) * 0.04f;
            cv4[q] = fmaxf(m2r - m1r*m1r, 0.f) + fmaxf(m2b - m1b*m1b, 0.f);
        }
        float* p = outb + (size_t)(y0 + ty) * W_ + (x0 + tx4);
        STORE4(20, cv4);
    }
}

extern "C" void kernel_launch(void* const* d_in, const int* in_sizes, int n_in,
                              void* d_out, int out_size, void* d_ws, size_t ws_size,
                              hipStream_t stream) {
    const float* bayer = (const float*)d_in[0];
    float* out = (float*)d_out;
    (void)in_sizes; (void)n_in; (void)out_size; (void)d_ws; (void)ws_size;

    init_k5_kernel<<<dim3(1), dim3(64), 0, stream>>>();
    dim3 grid(W_ / TILE, H_ / TILE, 4);
    bayer_feat_kernel<<<grid, dim3(256), 0, stream>>>(bayer, out);
}

// Round 7
// 66.421 us; speedup vs baseline: 15.7504x; 1.2596x over previous
//
#include <hip/hip_runtime.h>
#include <math.h>

#define H_ 768
#define W_ 768
#define TILE 32
#define EXT 36
#define BROW 44   // sBp row stride: 2 left-pad + 40 data + 2 slack (16B-aligned rows)
#define EPS_ 1e-6f

typedef float vfloat4 __attribute__((ext_vector_type(4)));

// normalized gabor45 kernel (precomputed offline, _norm applied); g135 = column mirror
__constant__ float GW[25] = {
   -0.00209120f, -0.01519473f, -0.06332027f, -0.00228457f,  0.03651120f,
   -0.01519473f, -0.08630971f,  0.00380376f,  0.11945652f, -0.00228457f,
   -0.06332027f,  0.00380376f,  0.17285313f,  0.00380376f, -0.06332027f,
   -0.00228457f,  0.11945652f,  0.00380376f, -0.08630971f, -0.01519473f,
    0.03651120f, -0.00228457f, -0.06332027f, -0.01519473f, -0.00209120f
};

__device__ __forceinline__ int refl(int i, int n) {
    i = (i < 0) ? -i : i;
    return (i >= n) ? (2 * n - 2 - i) : i;
}

// LDS layout (31872 B, no overlays):
//  sGG  [0,10368)      float2[36*36] (gx,gy)
//  sCD  [10368,20736)  float2[36*36] (rg,bg)
//  sBp  [20736,27776)  float[40*44]  bayer (+2 col shift)
//  sGPD [27776,31872)  float[32*32]

#define STORE4(ch, a) do { \
    vfloat4 _v = { (a)[0], (a)[1], (a)[2], (a)[3] }; \
    *(vfloat4*)(p + (size_t)(ch) * HW) = _v; \
} while (0)

__global__ __launch_bounds__(256, 3)
void bayer_feat_kernel(const float* __restrict__ in, float* __restrict__ out) {
    __shared__ __align__(16) char smem[31872];
    float2* const sGG  = (float2*)(smem);
    float2* const sCD  = (float2*)(smem + 10368);
    float*  const sBp  = (float*) (smem + 20736);
    float*  const sGPD = (float*) (smem + 27776);

    const int tid = threadIdx.x;
    const int x0 = blockIdx.x * TILE;
    const int y0 = blockIdx.y * TILE;
    const int bz = blockIdx.z;
    const float* __restrict__ inb = in + (size_t)bz * H_ * W_;
    const bool border = (x0 == 0) | (x0 + TILE == W_) | (y0 == 0) | (y0 + TILE == H_);

    // ---- phase 1: bayer tile + halo 4 ----
    if (border) {
        for (int i = tid; i < 1600; i += 256) {
            int iy = i / 40, ix = i - iy * 40;
            sBp[iy * BROW + ix + 2] = inb[refl(y0 - 4 + iy, H_) * W_ + refl(x0 - 4 + ix, W_)];
        }
    } else {
        for (int i = tid; i < 1600; i += 256) {
            int iy = i / 40, ix = i - iy * 40;
            sBp[iy * BROW + ix + 2] = inb[(y0 - 4 + iy) * W_ + (x0 - 4 + ix)];
        }
    }
    __syncthreads();

    const float w5c[5] = {1.f, 2.f, 3.f, 2.f, 1.f};

    // ---- phase 2: ext 36x36 -> gx/gy, rg/bg, gpd (reflect-at-fill) ----
    for (int i = tid; i < EXT * EXT; i += 256) {
        int ey = i / EXT, ex = i - ey * EXT;
        int ry, rx, p_r, p_c;
        if (border) {
            int py = refl(y0 - 2 + ey, H_), pxc = refl(x0 - 2 + ex, W_);
            ry = py - (y0 - 4); rx = pxc - (x0 - 4);
            p_r = py & 1; p_c = pxc & 1;
        } else {
            ry = ey + 2; rx = ex + 2;
            p_r = ey & 1; p_c = ex & 1;
        }
        const float* bC = sBp + ry * BROW + rx + 2;

        float bmm = bC[-BROW-1], bm0 = bC[-BROW], bmp = bC[-BROW+1];
        float b0m = bC[-1],                        b0p = bC[1];
        float bpm = bC[BROW-1],  bp0 = bC[BROW],  bpp = bC[BROW+1];
        sGG[i] = make_float2(((bmp - bmm) + 2.f*(b0p - b0m) + (bpp - bpm)) * 0.125f,
                             ((bpm - bmm) + 2.f*(bp0 - bm0) + (bpp - bmp)) * 0.125f);

        float A0 = 0.f, A1 = 0.f, B0 = 0.f, B1 = 0.f;
        #pragma unroll
        for (int dy = 0; dy < 5; ++dy) {
            const float* row = bC + (dy - 2) * BROW;
            float cs = row[-2] + 3.f*row[0] + row[2];
            float cd = 2.f*(row[-1] + row[1]);
            float wy = w5c[dy];
            if (dy & 1) { B0 += wy * cs; B1 += wy * cd; }
            else        { A0 += wy * cs; A1 += wy * cd; }
        }
        float rA0 = p_r ? B0 : A0;
        float rA1 = p_r ? B1 : A1;
        float rB0 = p_r ? A0 : B0;
        float rB1 = p_r ? A1 : B1;
        float n_gb = p_c ? rA1 : rA0;
        float n_b  = p_c ? rA0 : rA1;
        float n_r  = p_c ? rB1 : rB0;
        float n_gr = p_c ? rB0 : rB1;

        float inv_r  = p_r ? (p_c ? 0.05f   : 0.04f)   : (p_c ? 0.0625f : 0.05f);
        float inv_b  = p_r ? (p_c ? 0.05f   : 0.0625f) : (p_c ? 0.04f   : 0.05f);
        float inv_gr = p_r ? (p_c ? 0.04f   : 0.05f)   : (p_c ? 0.05f   : 0.0625f);
        float inv_gb = p_r ? (p_c ? 0.0625f : 0.05f)   : (p_c ? 0.05f   : 0.04f);
        float inv_g  = (p_r == p_c) ? 0.024390243902439025f : 0.025f;

        float fr  = n_r  * inv_r;
        float fb  = n_b  * inv_b;
        float fgr = n_gr * inv_gr;
        float fgb = n_gb * inv_gb;
        float fg  = (n_gr + n_gb) * inv_g;

        sCD[i] = make_float2(fr - fg, fb - fg);
        if (ey >= 2 && ey < 34 && ex >= 2 && ex < 34)
            sGPD[(ey - 2) * 32 + (ex - 2)] = fgr - fgb;
    }
    __syncthreads();

    const size_t HW = (size_t)H_ * W_;
    float* __restrict__ outb = out + (size_t)bz * 30 * HW;

    // ---- phase 3: pixel-quad, all 30 channels, zero post-store barriers ----
    {
        const int ty = tid >> 3;
        const int tx4 = (tid & 7) << 2;
        const int gy = y0 + ty;
        float* p = outb + (size_t)gy * W_ + (x0 + tx4);

        // part 0: direct 25-tap J (smooth5 of gx/gy products) + chroma moments (box5)
        float jxx[4] = {0,0,0,0}, jyy[4] = {0,0,0,0}, jxy[4] = {0,0,0,0};
        float m1r[4] = {0,0,0,0}, m2r[4] = {0,0,0,0};
        float m1b[4] = {0,0,0,0}, m2b[4] = {0,0,0,0};
        float gx4[4], gy4[4], rg4[4], bg4[4];

        #pragma unroll
        for (int dy = 0; dy < 5; ++dy) {
            const float wy = w5c[dy];
            float gxr[8], gyr[8];
            {
                const float4* g4 = (const float4*)(sGG + (ty + dy) * 36 + tx4);
                float4 a = g4[0], b = g4[1], c = g4[2], d = g4[3];
                gxr[0]=a.x; gyr[0]=a.y; gxr[1]=a.z; gyr[1]=a.w;
                gxr[2]=b.x; gyr[2]=b.y; gxr[3]=b.z; gyr[3]=b.w;
                gxr[4]=c.x; gyr[4]=c.y; gxr[5]=c.z; gyr[5]=c.w;
                gxr[6]=d.x; gyr[6]=d.y; gxr[7]=d.z; gyr[7]=d.w;
            }
            float px2[8], py2[8], pxy[8];
            #pragma unroll
            for (int c = 0; c < 8; ++c) {
                px2[c] = gxr[c]*gxr[c];
                py2[c] = gyr[c]*gyr[c];
                pxy[c] = gxr[c]*gyr[c];
            }
            #pragma unroll
            for (int q = 0; q < 4; ++q) {
                #pragma unroll
                for (int dx = 0; dx < 5; ++dx) {
                    const float w = wy * w5c[dx];
                    jxx[q] = fmaf(w, px2[q+dx], jxx[q]);
                    jyy[q] = fmaf(w, py2[q+dx], jyy[q]);
                    jxy[q] = fmaf(w, pxy[q+dx], jxy[q]);
                }
            }

            float cr[8], cb[8];
            {
                const float4* c4 = (const float4*)(sCD + (ty + dy) * 36 + tx4);
                float4 a = c4[0], b = c4[1], c_ = c4[2], d = c4[3];
                cr[0]=a.x; cb[0]=a.y; cr[1]=a.z; cb[1]=a.w;
                cr[2]=b.x; cb[2]=b.y; cr[3]=b.z; cb[3]=b.w;
                cr[4]=c_.x; cb[4]=c_.y; cr[5]=c_.z; cb[5]=c_.w;
                cr[6]=d.x; cb[6]=d.y; cr[7]=d.z; cb[7]=d.w;
            }
            float sr[8], sb[8];
            #pragma unroll
            for (int c = 0; c < 8; ++c) { sr[c] = cr[c]*cr[c]; sb[c] = cb[c]*cb[c]; }
            #pragma unroll
            for (int q = 0; q < 4; ++q) {
                m1r[q] += cr[q] + cr[q+1] + cr[q+2] + cr[q+3] + cr[q+4];
                m2r[q] += sr[q] + sr[q+1] + sr[q+2] + sr[q+3] + sr[q+4];
                m1b[q] += cb[q] + cb[q+1] + cb[q+2] + cb[q+3] + cb[q+4];
                m2b[q] += sb[q] + sb[q+1] + sb[q+2] + sb[q+3] + sb[q+4];
            }

            if (dy == 2) {   // center row: capture gx/gy and rg/bg for ch 0/1/15/16/4/19
                #pragma unroll
                for (int q = 0; q < 4; ++q) {
                    gx4[q] = gxr[q+2]; gy4[q] = gyr[q+2];
                    rg4[q] = cr[q+2];  bg4[q] = cb[q+2];
                }
            }
        }

        float an4[4], cv4[4];
        const float inv81 = 1.f / 81.f;
        #pragma unroll
        for (int q = 0; q < 4; ++q) {
            float xx = jxx[q] * inv81, yy = jyy[q] * inv81, xy = jxy[q] * inv81;
            float jd = 0.5f * (xx - yy);
            an4[q] = 2.f * sqrtf(jd*jd + xy*xy + EPS_) / (xx + yy + EPS_);
            float a1r = m1r[q] * 0.04f, a2r = m2r[q] * 0.04f;
            float a1b = m1b[q] * 0.04f, a2b = m2b[q] * 0.04f;
            cv4[q] = fmaxf(a2r - a1r*a1r, 0.f) + fmaxf(a2b - a1b*a1b, 0.f);
        }
        STORE4(8, an4);
        STORE4(20, cv4);
        STORE4(0, gx4);
        STORE4(1, gy4);
        STORE4(15, rg4);
        STORE4(16, bg4);
        {
            float gm4[4], ch4[4];
            #pragma unroll
            for (int q = 0; q < 4; ++q) {
                gm4[q] = sqrtf(gx4[q]*gx4[q] + gy4[q]*gy4[q] + EPS_);
                ch4[q] = sqrtf(rg4[q]*rg4[q] + bg4[q]*bg4[q] + EPS_);
            }
            STORE4(4, gm4);
            STORE4(19, ch4);
        }

        // part 1: bayer-tap channels
        float t[5][8];
        {
            const int rb = (ty + 2) * BROW + tx4 + 4;
            #pragma unroll
            for (int r = 0; r < 5; ++r) {
                float4 a = *(const float4*)&sBp[rb + r * BROW];
                float4 b = *(const float4*)&sBp[rb + r * BROW + 4];
                t[r][0]=a.x; t[r][1]=a.y; t[r][2]=a.z; t[r][3]=a.w;
                t[r][4]=b.x; t[r][5]=b.y; t[r][6]=b.z; t[r][7]=b.w;
            }
        }

        float gdm4[4], gda4[4];
        #pragma unroll
        for (int q = 0; q < 4; ++q) {
            float bmm=t[1][q+1], bm0=t[1][q+2], bmp=t[1][q+3];
            float b0m=t[2][q+1],                 b0p=t[2][q+3];
            float bpm=t[3][q+1], bp0=t[3][q+2], bpp=t[3][q+3];
            gdm4[q] = (-2.f*bmm - bm0 - b0m + b0p + bp0 + 2.f*bpp) * 0.125f;
            gda4[q] = (bm0 + 2.f*bmp - b0m + b0p - 2.f*bpm - bp0) * 0.125f;
        }
        STORE4(2, gdm4);
        STORE4(3, gda4);

        {
            float lap4[4], lmx4[4], lmn4[4];
            #pragma unroll
            for (int q = 0; q < 4; ++q) {
                float hxx = t[2][q+1] - 2.f*t[2][q+2] + t[2][q+3];
                float hyy = t[1][q+2] - 2.f*t[2][q+2] + t[3][q+2];
                float hxy = (t[1][q+1] - t[1][q+3] - t[3][q+1] + t[3][q+3]) * 0.25f;
                lap4[q] = hxx + hyy;
                float hm = 0.5f * (hxx + hyy);
                float hsd = 0.5f * (hxx - hyy);
                float hs = sqrtf(hsd*hsd + hxy*hxy + EPS_);
                lmx4[q] = hm + hs; lmn4[q] = hm - hs;
            }
            STORE4(5, lap4); STORE4(6, lmx4); STORE4(7, lmn4);
        }
        {
            float dv4[4];
            #pragma unroll
            for (int q = 0; q < 4; ++q) {
                float md  = 0.25f * (gx4[q] + gy4[q] + gdm4[q] + gda4[q]);
                float m2d = 0.25f * (gx4[q]*gx4[q] + gy4[q]*gy4[q] + gdm4[q]*gdm4[q] + gda4[q]*gda4[q]);
                dv4[q] = m2d - md * md;
            }
            STORE4(9, dv4);
        }

        float hf4[4];
        {
            float gir4[4];
            #pragma unroll
            for (int q = 0; q < 4; ++q) {
                float sumx = t[1][q+2] + t[2][q+1] + t[2][q+3] + t[3][q+2];
                float sumc = t[1][q+1] + t[1][q+3] + t[3][q+1] + t[3][q+3];
                hf4[q] = (sumc - 2.f*sumx + 4.f*t[2][q+2]) * 0.0625f;
                float gcross = 0.25f * sumx;
                gir4[q] = ((ty & 1) == (q & 1)) ? (t[2][q+2] - gcross) : 0.f;
            }
            STORE4(17, gir4);
        }
        {
            float pr = (float)(ty & 1);
            float rm4[4] = {pr, 0.f, pr, 0.f};
            float bm4[4] = {0.f, 1.f - pr, 0.f, 1.f - pr};
            float gm4[4] = {1.f - pr, pr, 1.f - pr, pr};
            STORE4(11, rm4); STORE4(12, gm4); STORE4(13, bm4);
        }
        {
            float dgc4[4];
            #pragma unroll
            for (int q = 0; q < 4; ++q) {
                float gh = 0.5f*(t[2][q+1] + t[2][q+2] + t[2][q+3]) - 0.25f*(t[2][q] + t[2][q+4]);
                float gv = 0.5f*(t[1][q+2] + t[2][q+2] + t[3][q+2]) - 0.25f*(t[0][q+2] + t[4][q+2]);
                dgc4[q] = fabsf(gh - gv);
            }
            STORE4(18, dgc4);
        }

        // gabors (hardcoded weights; g135 = column mirror)
        {
            float g45[4] = {0.f,0.f,0.f,0.f}, g135[4] = {0.f,0.f,0.f,0.f};
            #pragma unroll
            for (int dy = 0; dy < 5; ++dy) {
                #pragma unroll
                for (int dx = 0; dx < 5; ++dx) {
                    const float w = GW[dy * 5 + dx];
                    #pragma unroll
                    for (int q = 0; q < 4; ++q) {
                        g45[q]  = fmaf(w, t[dy][q + dx],     g45[q]);
                        g135[q] = fmaf(w, t[dy][q + 4 - dx], g135[q]);
                    }
                }
            }
            float oe4[4];
            #pragma unroll
            for (int q = 0; q < 4; ++q) oe4[q] = sqrtf(g45[q]*g45[q] + g135[q]*g135[q] + EPS_);
            STORE4(10, oe4);
        }

        // separable 5x5 bank via register column-profiles
        {
            float Vo[8], Va[8], Vs_[8], Vc_[8], Vd_[8];
            #pragma unroll
            for (int c = 0; c < 8; ++c) {
                float v0=t[0][c], v1=t[1][c], v2=t[2][c], v3=t[3][c], v4=t[4][c];
                Vo[c] = v0 + v1 + v2 + v3 + v4;
                Va[c] = v0 - v1 + v2 - v3 + v4;
                Vs_[c] = 0.95105651629515f*(v1 - v4) + 0.58778525229247f*(v2 - v3);
                Vc_[c] = v0 + 0.30901699437495f*(v1 + v4) - 0.80901699437495f*(v2 + v3);
                Vd_[c] = 0.80901699437495f*(v0 + v4) - 0.30901699437495f*(v1 + v3) - v2;
            }
            float cb4[4], sh4[4], sv4[4], sx4[4], sy4[4], ph4[4], hb4[4];
            #pragma unroll
            for (int q = 0; q < 4; ++q) {
                float box = Vo[q] + Vo[q+1] + Vo[q+2] + Vo[q+3] + Vo[q+4];
                float shr = Vo[q] - Vo[q+1] + Vo[q+2] - Vo[q+3] + Vo[q+4];
                float sxr = 0.95105651629515f*(Vo[q+1] - Vo[q+4]) + 0.58778525229247f*(Vo[q+2] - Vo[q+3]);
                float pxr = Vo[q] + 0.30901699437495f*(Vo[q+1] + Vo[q+4]) - 0.80901699437495f*(Vo[q+2] + Vo[q+3]);
                float cbr = Va[q] - Va[q+1] + Va[q+2] - Va[q+3] + Va[q+4];
                float svr = Va[q] + Va[q+1] + Va[q+2] + Va[q+3] + Va[q+4];
                float syr = Vs_[q] + Vs_[q+1] + Vs_[q+2] + Vs_[q+3] + Vs_[q+4];
                float pyr = Vc_[q] + Vc_[q+1] + Vc_[q+2] + Vc_[q+3] + Vc_[q+4];
                float dctr = 0.80901699437495f*(Vd_[q] + Vd_[q+4]) - 0.30901699437495f*(Vd_[q+1] + Vd_[q+3]) - Vd_[q+2];

                cb4[q] = fabsf((cbr - 0.04f * box) * 0.04006410256410f);
                sh4[q] = (shr - 0.2f * box) * 0.04166666666667f;
                sv4[q] = (svr - 0.2f * box) * 0.04166666666667f;
                sx4[q] = sxr * 0.06498394f;
                sy4[q] = syr * 0.06498394f;
                float px_n = pxr * 0.06180339887f;
                float py_n = pyr * 0.06180339887f;
                ph4[q] = sqrtf(px_n*px_n + py_n*py_n + EPS_);
                float dct_n = dctr * 0.09549150281f;
                hb4[q] = sqrtf(dct_n*dct_n + hf4[q]*hf4[q] + EPS_);
            }
            STORE4(21, cb4); STORE4(22, sh4); STORE4(23, sv4);
            STORE4(24, sh4); STORE4(25, sv4); STORE4(26, ph4);
            STORE4(27, sx4); STORE4(28, sy4); STORE4(29, hb4);
        }

        // gpd
        {
            float4 gp = *(const float4*)(sGPD + ty * 32 + tx4);
            float gp4[4] = {gp.x, gp.y, gp.z, gp.w};
            STORE4(14, gp4);
        }
    }
}

extern "C" void kernel_launch(void* const* d_in, const int* in_sizes, int n_in,
                              void* d_out, int out_size, void* d_ws, size_t ws_size,
                              hipStream_t stream) {
    const float* bayer = (const float*)d_in[0];
    float* out = (float*)d_out;
    (void)in_sizes; (void)n_in; (void)out_size; (void)d_ws; (void)ws_size;

    dim3 grid(W_ / TILE, H_ / TILE, 4);
    bayer_feat_kernel<<<grid, dim3(256), 0, stream>>>(bayer, out);
}